// Round 10
// baseline (1448.207 us; speedup 1.0000x reference)
//
#include <hip/hip_runtime.h>
#include <hip/hip_bf16.h>
#include <stdint.h>

typedef __attribute__((ext_vector_type(8))) short bf16x8;
typedef __attribute__((ext_vector_type(4))) float f32x4;
typedef unsigned short ushort_t;

typedef __attribute__((address_space(1))) char as1_char;
typedef __attribute__((address_space(3))) char as3_char;

__device__ __forceinline__ void gload_lds16(const void* g, void* l) {
  __builtin_amdgcn_global_load_lds((as1_char*)g, (as3_char*)l, 16, 0, 0);
}

template <int N> __device__ __forceinline__ void waitvm() {
  asm volatile("s_waitcnt vmcnt(%0)" :: "n"(N) : "memory");
}

__device__ __forceinline__ unsigned short f2bf(float f) {
  union { float f; unsigned u; } c; c.f = f;
  unsigned u = c.u;
  return (unsigned short)((u + 0x7fffu + ((u >> 16) & 1u)) >> 16);
}

// ---------------- RMSNorm: fp32 [tok][2048] -> bf16 ----------------
__global__ __launch_bounds__(256)
void rmsnorm_kernel(const float* __restrict__ x, unsigned short* __restrict__ out) {
  const int tok = blockIdx.x;
  const int tid = threadIdx.x;
  const float4* xr = (const float4*)(x + (size_t)tok * 2048);
  float4 a = xr[tid];
  float4 b = xr[tid + 256];
  float s = a.x*a.x + a.y*a.y + a.z*a.z + a.w*a.w
          + b.x*b.x + b.y*b.y + b.z*b.z + b.w*b.w;
  #pragma unroll
  for (int m = 1; m < 64; m <<= 1) s += __shfl_xor(s, m);
  __shared__ float ws4[4];
  if ((tid & 63) == 0) ws4[tid >> 6] = s;
  __syncthreads();
  const float tot = ws4[0] + ws4[1] + ws4[2] + ws4[3];
  const float r = rsqrtf(tot * (1.0f / 2048.0f));
  ushort4 o1, o2;
  o1.x = f2bf(a.x * r); o1.y = f2bf(a.y * r); o1.z = f2bf(a.z * r); o1.w = f2bf(a.w * r);
  o2.x = f2bf(b.x * r); o2.y = f2bf(b.y * r); o2.z = f2bf(b.z * r); o2.w = f2bf(b.w * r);
  ushort4* orow = (ushort4*)(out + (size_t)tok * 2048);
  orow[tid] = o1;
  orow[tid + 256] = o2;
}

// ------------- transpose + convert: fp32 [R][C] -> bf16 [C][R] -------------
__global__ __launch_bounds__(256)
void transpose_cvt(const float* __restrict__ in, unsigned short* __restrict__ out,
                   int R, int C) {
  __shared__ float t[32][33];
  const int c0 = blockIdx.x * 32, r0 = blockIdx.y * 32;
  const int tx = threadIdx.x, ty = threadIdx.y;
  #pragma unroll
  for (int i = 0; i < 4; i++)
    t[ty + 8 * i][tx] = in[(size_t)(r0 + ty + 8 * i) * C + (c0 + tx)];
  __syncthreads();
  #pragma unroll
  for (int i = 0; i < 4; i++)
    out[(size_t)(c0 + ty + 8 * i) * R + (r0 + tx)] = f2bf(t[tx][ty + 8 * i]);
}

// ------------- convert only: fp32 -> bf16 (layout preserved) -------------
__global__ __launch_bounds__(256)
void cvt_bf16_kernel(const float* __restrict__ in, unsigned short* __restrict__ out, int n4) {
  const int i = blockIdx.x * 256 + threadIdx.x;
  if (i < n4) {
    float4 v = ((const float4*)in)[i];
    ushort4 o; o.x = f2bf(v.x); o.y = f2bf(v.y); o.z = f2bf(v.z); o.w = f2bf(v.w);
    ((ushort4*)out)[i] = o;
  }
}

// ====== GEMM v2: BM=256, BN=128, BK=64, 8 waves (4Mx2N), ring-3 LDS, ======
// ====== SOFTWARE-PIPELINED frag loads: ds_read(t+1) overlaps MFMA(t) ======
// Loop unrolled x2 with named frag sets (rule: no runtime-indexed vec arrays).
// Safety: lgkmcnt(0) before each barrier drains prior-tile frag reads (already
// consumed by MFMA, ~free) => stage(t+2)->slot(t-1) writes (issued after the
// barrier, landing >=200cy later) can never race a pending reader.
// EPI 0: fused QKV regions (V^T to ob2). EPI 2: +bias ReLU6. EPI 3: fp32 res+acc.
template <int EPI>
__global__ __launch_bounds__(512, 2)
void gemm_r3(const ushort_t* __restrict__ A, const ushort_t* __restrict__ B,
             int K, int N,
             ushort_t* ob0, ushort_t* ob1, ushort_t* ob2, float* outf,
             const float* __restrict__ res, const float* __restrict__ bias,
             int nbx) {
  constexpr int SLOT = 49152;
  __shared__ __align__(16) char smem[3 * SLOT];

  const int tid = threadIdx.x;
  const int lane = tid & 63;
  const int wid = tid >> 6;
  const int wm = wid >> 1, wn = wid & 1;
  const int ln15 = lane & 15, g = lane >> 4;

  int wg = blockIdx.x;
  const int cpx = gridDim.x >> 3;
  wg = (wg & 7) * cpx + (wg >> 3);
  const int bx = wg % nbx, by = wg / nbx;
  const int m0 = by * 256, n0 = bx * 128;

  const char* Ab = (const char*)(A + (size_t)m0 * K);
  const char* Bb = (const char*)(B + (size_t)n0 * K);
  const size_t rowb = (size_t)K * 2;
  const int NT = K >> 6;            // always even (K multiple of 128)

  auto stage = [&](int t, int s) {
    char* As = smem + s * SLOT;
    char* Bs = As + 32768;
    const size_t kb = (size_t)t * 128;
    #pragma unroll
    for (int i = 0; i < 4; i++) {
      const int o = i * 8192 + tid * 16;
      const int row = o >> 7, col = o & 127;
      gload_lds16(Ab + (size_t)row * rowb + kb + (col ^ ((row & 7) << 4)), As + o);
    }
    #pragma unroll
    for (int i = 0; i < 2; i++) {
      const int o = i * 8192 + tid * 16;
      const int row = o >> 7, col = o & 127;
      gload_lds16(Bb + (size_t)row * rowb + kb + (col ^ ((row & 7) << 4)), Bs + o);
    }
  };

  f32x4 acc[4][4] = {};
  bf16x8 afA[4][2], bfA[4][2], afB[4][2], bfB[4][2];

  auto LD = [&](int s, bf16x8 (&af)[4][2], bf16x8 (&bf)[4][2]) {
    const char* As = smem + s * SLOT;
    const char* Bs = As + 32768;
    #pragma unroll
    for (int mi = 0; mi < 4; mi++) {
      const int row = wm * 64 + mi * 16 + ln15;
      #pragma unroll
      for (int kk = 0; kk < 2; kk++)
        af[mi][kk] = *(const bf16x8*)(As + row * 128 + ((kk * 64 + g * 16) ^ ((row & 7) << 4)));
    }
    #pragma unroll
    for (int ni = 0; ni < 4; ni++) {
      const int row = wn * 64 + ni * 16 + ln15;
      #pragma unroll
      for (int kk = 0; kk < 2; kk++)
        bf[ni][kk] = *(const bf16x8*)(Bs + row * 128 + ((kk * 64 + g * 16) ^ ((row & 7) << 4)));
    }
  };
  auto MM = [&](bf16x8 (&af)[4][2], bf16x8 (&bf)[4][2]) {
    __builtin_amdgcn_s_setprio(1);
    #pragma unroll
    for (int kk = 0; kk < 2; kk++)
      #pragma unroll
      for (int mi = 0; mi < 4; mi++)
        #pragma unroll
        for (int ni = 0; ni < 4; ni++)
          acc[mi][ni] = __builtin_amdgcn_mfma_f32_16x16x32_bf16(af[mi][kk], bf[ni][kk], acc[mi][ni], 0, 0, 0);
    __builtin_amdgcn_s_setprio(0);
  };

  stage(0, 0); stage(1, 1);
  waitvm<6>();
  __builtin_amdgcn_s_barrier();
  LD(0, afA, bfA);

  int slot = 0;                      // slot of tile t at loop top (t even)
  for (int t = 0; t < NT; t += 2) {
    // ---- even: compute t (set A), prefetch regs for t+1 (set B) ----
    {
      const int s2 = (slot + 2 >= 3) ? slot - 1 : slot + 2;
      if (t + 2 < NT) stage(t + 2, s2);
      if (t + 2 < NT) waitvm<6>(); else waitvm<0>();
      asm volatile("s_waitcnt lgkmcnt(0)" ::: "memory");
      __builtin_amdgcn_s_barrier();
      const int s1 = (slot + 1 >= 3) ? 0 : slot + 1;
      LD(s1, afB, bfB);                       // t+1 < NT always (NT even)
      __builtin_amdgcn_sched_barrier(0x7);    // MFMA may not hoist above; DS may not sink
      MM(afA, bfA);
    }
    // ---- odd: compute t+1 (set B), prefetch regs for t+2 (set A) ----
    {
      const int sB = (slot + 1 >= 3) ? 0 : slot + 1;   // slot of t+1
      const int s3 = (sB + 2 >= 3) ? sB - 1 : sB + 2;  // slot of t+3
      if (t + 3 < NT) stage(t + 3, s3);
      if (t + 3 < NT) waitvm<6>(); else waitvm<0>();
      asm volatile("s_waitcnt lgkmcnt(0)" ::: "memory");
      __builtin_amdgcn_s_barrier();
      if (t + 2 < NT) {
        const int s1 = (sB + 1 >= 3) ? 0 : sB + 1;
        LD(s1, afA, bfA);
        __builtin_amdgcn_sched_barrier(0x7);
        MM(afB, bfB);
      } else {
        MM(afB, bfB);
      }
    }
    slot = (slot + 2 >= 3) ? slot - 1 : slot + 2;
  }

  // ---------------- epilogue (from registers) ----------------
  #pragma unroll
  for (int mi = 0; mi < 4; mi++) {
    const int mrow = m0 + wm * 64 + mi * 16 + g * 4;
    #pragma unroll
    for (int ni = 0; ni < 4; ni++) {
      const int ncol = n0 + wn * 64 + ni * 16 + ln15;
      if (EPI == 0) {
        const int region = n0 >> 11;
        if (region == 0) {
          #pragma unroll
          for (int r = 0; r < 4; r++)
            ob0[(size_t)(mrow + r) * 2048 + ncol] = f2bf(acc[mi][ni][r]);
        } else if (region == 1) {
          #pragma unroll
          for (int r = 0; r < 4; r++)
            ob1[(size_t)(mrow + r) * 2048 + (ncol - 2048)] = f2bf(acc[mi][ni][r]);
        } else {
          const int bb = mrow >> 11, ss = mrow & 2047;
          const int ncv = ncol - 4096;
          const int hh = ncv >> 7, dd = ncv & 127;
          ushort4 v;
          v.x = f2bf(acc[mi][ni][0]); v.y = f2bf(acc[mi][ni][1]);
          v.z = f2bf(acc[mi][ni][2]); v.w = f2bf(acc[mi][ni][3]);
          *(ushort4*)(ob2 + ((size_t)((bb * 16 + hh) * 128 + dd)) * 2048 + ss) = v;
        }
      } else if (EPI == 2) {
        const float bv = bias[ncol];
        #pragma unroll
        for (int r = 0; r < 4; r++) {
          float v = acc[mi][ni][r] + bv;
          v = fminf(fmaxf(v, 0.0f), 6.0f);
          ob0[(size_t)(mrow + r) * N + ncol] = f2bf(v);
        }
      } else {
        const float bv = bias ? bias[ncol] : 0.0f;
        #pragma unroll
        for (int r = 0; r < 4; r++) {
          const size_t idx = (size_t)(mrow + r) * N + ncol;
          outf[idx] = res[idx] + acc[mi][ni][r] + bv;
        }
      }
    }
  }
}

// ------- Flash attention (causal), QBLK=128, KVBLK=64, 8 waves, 2 blocks/CU -------
__global__ __launch_bounds__(512, 2)
void attn_kernel(const unsigned short* __restrict__ Qg,
                 const unsigned short* __restrict__ Kg,
                 const unsigned short* __restrict__ Vg,
                 unsigned short* __restrict__ Og) {
  __shared__ __align__(16) char smem[65536];
  const int tid = threadIdx.x, lane = tid & 63, wid = tid >> 6;
  const int g = lane >> 4, qq = lane & 15;
  const int pairx = blockIdx.x, h = blockIdx.y, b = blockIdx.z;

  auto stage = [&](int kv0, char* kdst, char* vdst) {
    #pragma unroll
    for (int i = 0; i < 2; i++) {
      const int oo = i * 8192 + tid * 16;
      const int rK = oo >> 8;
      const int sK = (oo & 255) ^ ((rK & 7) << 4);
      gload_lds16((const char*)Kg + ((size_t)(b * 2048 + kv0 + rK) * 2048 + h * 128) * 2 + sK,
                  kdst + oo);
      const int rV = oo >> 7;
      const int sV = (oo & 127) ^ ((rV & 7) << 4);
      gload_lds16((const char*)Vg + ((size_t)((b * 16 + h) * 128 + rV) * 2048 + kv0) * 2 + sV,
                  vdst + oo);
    }
  };

  for (int half = 0; half < 2; ++half) {
    const int qb8 = half ? (15 - pairx) : pairx;
    const int q0 = qb8 * 128;
    const int myq = q0 + wid * 16 + qq;
    const int nt = 2 * qb8 + 2;

    bf16x8 qf[4];
    const unsigned short* qp = Qg + ((size_t)(b * 2048 + myq)) * 2048 + h * 128 + g * 8;
    #pragma unroll
    for (int ks = 0; ks < 4; ks++) qf[ks] = *(const bf16x8*)(qp + ks * 32);

    stage(0, smem, smem + 16384);

    float m_run = -1e30f, l_run = 0.0f;
    f32x4 oacc[8] = {};

    for (int t = 0; t < nt; ++t) {
      const int cur = t & 1;
      char* kbc = cur ? smem + 32768 : smem;
      char* vbc = cur ? smem + 49152 : smem + 16384;
      char* kbn = cur ? smem : smem + 32768;
      char* vbn = cur ? smem + 16384 : smem + 49152;

      if (t + 1 < nt) {
        stage((t + 1) * 64, kbn, vbn);
        asm volatile("s_waitcnt vmcnt(4)" ::: "memory");
      } else {
        asm volatile("s_waitcnt vmcnt(0)" ::: "memory");
      }
      __builtin_amdgcn_s_barrier();
      asm volatile("" ::: "memory");

      const int kv0 = t * 64;

      f32x4 st[4] = {};
      __builtin_amdgcn_s_setprio(1);
      #pragma unroll
      for (int ks = 0; ks < 4; ks++) {
        #pragma unroll
        for (int f = 0; f < 4; f++) {
          const int row = f * 16 + qq;
          const int cb = ks * 64 + g * 16;
          bf16x8 kf = *(const bf16x8*)(kbc + row * 256 + (cb ^ ((row & 7) << 4)));
          st[f] = __builtin_amdgcn_mfma_f32_16x16x32_bf16(kf, qf[ks], st[f], 0, 0, 0);
        }
      }
      __builtin_amdgcn_s_setprio(0);

      float p[4][4];
      float tmax = -3.0e38f;
      const bool diag = (kv0 + 63 > q0 + wid * 16);
      #pragma unroll
      for (int f = 0; f < 4; f++) {
        #pragma unroll
        for (int r = 0; r < 4; r++) {
          float v = st[f][r] * 0.08838834764831845f;
          if (diag) {
            const int kv = kv0 + f * 16 + g * 4 + r;
            if (kv > myq) v = -3.0e38f;
          }
          p[f][r] = v;
          tmax = fmaxf(tmax, v);
        }
      }
      tmax = fmaxf(tmax, __shfl_xor(tmax, 16));
      tmax = fmaxf(tmax, __shfl_xor(tmax, 32));
      const float m_new = fmaxf(m_run, tmax);
      const float sf = __expf(m_run - m_new);
      m_run = m_new;
      float tsum = 0.0f;
      #pragma unroll
      for (int f = 0; f < 4; f++) {
        #pragma unroll
        for (int r = 0; r < 4; r++) {
          p[f][r] = __expf(p[f][r] - m_new);
          tsum += p[f][r];
        }
      }
      tsum += __shfl_xor(tsum, 16);
      tsum += __shfl_xor(tsum, 32);
      l_run = l_run * sf + tsum;

      unsigned pk[4][2];
      #pragma unroll
      for (int f = 0; f < 4; f++) {
        pk[f][0] = (unsigned)f2bf(p[f][0]) | ((unsigned)f2bf(p[f][1]) << 16);
        pk[f][1] = (unsigned)f2bf(p[f][2]) | ((unsigned)f2bf(p[f][3]) << 16);
      }
      bf16x8 pa[2];
      const int sel = g >> 1;
      #pragma unroll
      for (int ks2 = 0; ks2 < 2; ks2++) {
        unsigned d[4];
        #pragma unroll
        for (int u = 0; u < 2; u++) {
          const int sl = qq + (((2 * g + u) & 3) << 4);
          const unsigned lo0 = (unsigned)__shfl((int)pk[2 * ks2][0], sl);
          const unsigned hi0 = (unsigned)__shfl((int)pk[2 * ks2 + 1][0], sl);
          const unsigned lo1 = (unsigned)__shfl((int)pk[2 * ks2][1], sl);
          const unsigned hi1 = (unsigned)__shfl((int)pk[2 * ks2 + 1][1], sl);
          d[2 * u]     = sel ? hi0 : lo0;
          d[2 * u + 1] = sel ? hi1 : lo1;
        }
        union { unsigned u[4]; bf16x8 v; } cv;
        cv.u[0] = d[0]; cv.u[1] = d[1]; cv.u[2] = d[2]; cv.u[3] = d[3];
        pa[ks2] = cv.v;
      }

      float sfr[4];
      #pragma unroll
      for (int r = 0; r < 4; r++) sfr[r] = __shfl(sf, g * 4 + r);
      #pragma unroll
      for (int nf = 0; nf < 8; nf++) {
        oacc[nf][0] *= sfr[0]; oacc[nf][1] *= sfr[1];
        oacc[nf][2] *= sfr[2]; oacc[nf][3] *= sfr[3];
      }
      __builtin_amdgcn_s_setprio(1);
      #pragma unroll
      for (int ks2 = 0; ks2 < 2; ks2++) {
        #pragma unroll
        for (int nf = 0; nf < 8; nf++) {
          const int row = nf * 16 + qq;
          const int cb = ks2 * 64 + g * 16;
          bf16x8 vf = *(const bf16x8*)(vbc + row * 128 + (cb ^ ((row & 7) << 4)));
          oacc[nf] = __builtin_amdgcn_mfma_f32_16x16x32_bf16(pa[ks2], vf, oacc[nf], 0, 0, 0);
        }
      }
      __builtin_amdgcn_s_setprio(0);

      asm volatile("" ::: "memory");
      __builtin_amdgcn_s_barrier();
    }

    asm volatile("" ::: "memory");
    const float inv = 1.0f / l_run;
    float invr[4];
    #pragma unroll
    for (int r = 0; r < 4; r++) invr[r] = __shfl(inv, g * 4 + r);

    float* Osm = (float*)smem;
    #pragma unroll
    for (int pass = 0; pass < 2; ++pass) {
      if ((wid >> 2) == pass) {
        const int w4 = wid & 3;
        #pragma unroll
        for (int nf = 0; nf < 8; nf++) {
          #pragma unroll
          for (int r = 0; r < 4; r++)
            Osm[(w4 * 16 + g * 4 + r) * 132 + nf * 16 + qq] = oacc[nf][r] * invr[r];
        }
      }
      __syncthreads();
      #pragma unroll
      for (int it = 0; it < 2; it++) {
        const int row = it * 32 + (tid >> 4);
        const int c0 = (tid & 15) * 8;
        const float* src = &Osm[row * 132 + c0];
        uint4 w;
        w.x = (unsigned)f2bf(src[0]) | ((unsigned)f2bf(src[1]) << 16);
        w.y = (unsigned)f2bf(src[2]) | ((unsigned)f2bf(src[3]) << 16);
        w.z = (unsigned)f2bf(src[4]) | ((unsigned)f2bf(src[5]) << 16);
        w.w = (unsigned)f2bf(src[6]) | ((unsigned)f2bf(src[7]) << 16);
        *(uint4*)(Og + (size_t)(b * 2048 + q0 + pass * 64 + row) * 2048 + h * 128 + c0) = w;
      }
      __syncthreads();
    }
  }
}

extern "C" void kernel_launch(void* const* d_in, const int* in_sizes, int n_in,
                              void* d_out, int out_size, void* d_ws, size_t ws_size,
                              hipStream_t stream) {
  (void)in_sizes; (void)n_in; (void)out_size; (void)ws_size;
  const float* x  = (const float*)d_in[0];
  const float* wq = (const float*)d_in[1];
  const float* wk = (const float*)d_in[2];
  const float* wv = (const float*)d_in[3];
  const float* wo = (const float*)d_in[4];
  const float* w1 = (const float*)d_in[5];
  const float* b1 = (const float*)d_in[6];
  const float* w2 = (const float*)d_in[7];
  const float* b2 = (const float*)d_in[8];
  float* out = (float*)d_out;
  char* ws = (char*)d_ws;

  // workspace layout (bytes); total = 184,549,376
  ushort_t* wqkvT = (ushort_t*)(ws + 0);            // [6144 n][2048 k] (q|k|v)
  ushort_t* wqT = wqkvT;
  ushort_t* wkT = (ushort_t*)(ws + 8388608);
  ushort_t* wvT = (ushort_t*)(ws + 16777216);
  ushort_t* woC = (ushort_t*)(ws + 25165824);       // [2048 e][2048 hk]
  ushort_t* w1T = (ushort_t*)(ws + 33554432);       // [8192 f][2048 e]
  ushort_t* w2T = (ushort_t*)(ws + 67108864);       // [2048 e][8192 f]
  ushort_t* h1  = (ushort_t*)(ws + 100663296);      // [4096][2048]
  ushort_t* Qb  = (ushort_t*)(ws + 117440512);
  ushort_t* Kb  = (ushort_t*)(ws + 134217728);
  ushort_t* Vt  = (ushort_t*)(ws + 150994944);      // [b,h,d,s]
  ushort_t* hid = h1;                                // [4096][8192] aliases h1/Q/K/V (dead)
  ushort_t* att = (ushort_t*)(ws + 167772160);
  ushort_t* h2  = att;                               // aliases att (dead then)

  const dim3 tb(32, 8);
  transpose_cvt<<<dim3(64, 64), tb, 0, stream>>>(wq, wqT, 2048, 2048);
  transpose_cvt<<<dim3(64, 64), tb, 0, stream>>>(wk, wkT, 2048, 2048);
  transpose_cvt<<<dim3(64, 64), tb, 0, stream>>>(wv, wvT, 2048, 2048);
  cvt_bf16_kernel<<<4096, 256, 0, stream>>>(wo, woC, 1048576);
  transpose_cvt<<<dim3(256, 64), tb, 0, stream>>>(w1, w1T, 2048, 8192);
  transpose_cvt<<<dim3(64, 256), tb, 0, stream>>>(w2, w2T, 8192, 2048);

  // h1 = rmsnorm(x)
  rmsnorm_kernel<<<4096, 256, 0, stream>>>(x, h1);
  // fused QKV (pipelined r3, 768 blocks = 3 exact rounds): Q->Qb, K->Kb, V->Vt
  gemm_r3<0><<<48 * 16, 512, 0, stream>>>(h1, wqkvT, 2048, 6144,
                                          Qb, Kb, Vt, nullptr, nullptr, nullptr, 48);
  // attention
  attn_kernel<<<dim3(8, 16, 2), 512, 0, stream>>>(Qb, Kb, Vt, att);
  // x1 = x + attn @ w_o -> d_out (fp32)
  gemm_r3<3><<<16 * 16, 512, 0, stream>>>(att, woC, 2048, 2048,
                                          nullptr, nullptr, nullptr, out, x, nullptr, 16);
  // h2 = rmsnorm(x1)
  rmsnorm_kernel<<<4096, 256, 0, stream>>>(out, h2);
  // hidden = relu6(h2 @ w1 + b1)  (pipelined r3, 1024 blocks = 4 exact rounds)
  gemm_r3<2><<<64 * 16, 512, 0, stream>>>(h2, w1T, 2048, 8192,
                                          hid, nullptr, nullptr, nullptr, nullptr, b1, 64);
  // out = x1 + hidden @ w2 + b2
  gemm_r3<3><<<16 * 16, 512, 0, stream>>>(hid, w2T, 8192, 2048,
                                          nullptr, nullptr, nullptr, out, out, b2, 16);
}

// Round 11
// 1445.971 us; speedup vs baseline: 1.0015x; 1.0015x over previous
//
#include <hip/hip_runtime.h>
#include <hip/hip_bf16.h>
#include <stdint.h>

typedef __attribute__((ext_vector_type(8))) short bf16x8;
typedef __attribute__((ext_vector_type(4))) float f32x4;
typedef unsigned short ushort_t;

typedef __attribute__((address_space(1))) char as1_char;
typedef __attribute__((address_space(3))) char as3_char;

__device__ __forceinline__ void gload_lds16(const void* g, void* l) {
  __builtin_amdgcn_global_load_lds((as1_char*)g, (as3_char*)l, 16, 0, 0);
}

template <int N> __device__ __forceinline__ void waitvm() {
  asm volatile("s_waitcnt vmcnt(%0)" :: "n"(N) : "memory");
}

__device__ __forceinline__ unsigned short f2bf(float f) {
  union { float f; unsigned u; } c; c.f = f;
  unsigned u = c.u;
  return (unsigned short)((u + 0x7fffu + ((u >> 16) & 1u)) >> 16);
}

// ---------------- RMSNorm: fp32 [tok][2048] -> bf16 ----------------
__global__ __launch_bounds__(256)
void rmsnorm_kernel(const float* __restrict__ x, unsigned short* __restrict__ out) {
  const int tok = blockIdx.x;
  const int tid = threadIdx.x;
  const float4* xr = (const float4*)(x + (size_t)tok * 2048);
  float4 a = xr[tid];
  float4 b = xr[tid + 256];
  float s = a.x*a.x + a.y*a.y + a.z*a.z + a.w*a.w
          + b.x*b.x + b.y*b.y + b.z*b.z + b.w*b.w;
  #pragma unroll
  for (int m = 1; m < 64; m <<= 1) s += __shfl_xor(s, m);
  __shared__ float ws4[4];
  if ((tid & 63) == 0) ws4[tid >> 6] = s;
  __syncthreads();
  const float tot = ws4[0] + ws4[1] + ws4[2] + ws4[3];
  const float r = rsqrtf(tot * (1.0f / 2048.0f));
  ushort4 o1, o2;
  o1.x = f2bf(a.x * r); o1.y = f2bf(a.y * r); o1.z = f2bf(a.z * r); o1.w = f2bf(a.w * r);
  o2.x = f2bf(b.x * r); o2.y = f2bf(b.y * r); o2.z = f2bf(b.z * r); o2.w = f2bf(b.w * r);
  ushort4* orow = (ushort4*)(out + (size_t)tok * 2048);
  orow[tid] = o1;
  orow[tid + 256] = o2;
}

// ------------- transpose + convert: fp32 [R][C] -> bf16 [C][R] -------------
__global__ __launch_bounds__(256)
void transpose_cvt(const float* __restrict__ in, unsigned short* __restrict__ out,
                   int R, int C) {
  __shared__ float t[32][33];
  const int c0 = blockIdx.x * 32, r0 = blockIdx.y * 32;
  const int tx = threadIdx.x, ty = threadIdx.y;
  #pragma unroll
  for (int i = 0; i < 4; i++)
    t[ty + 8 * i][tx] = in[(size_t)(r0 + ty + 8 * i) * C + (c0 + tx)];
  __syncthreads();
  #pragma unroll
  for (int i = 0; i < 4; i++)
    out[(size_t)(c0 + ty + 8 * i) * R + (r0 + tx)] = f2bf(t[tx][ty + 8 * i]);
}

// ------------- convert only: fp32 -> bf16 (layout preserved) -------------
__global__ __launch_bounds__(256)
void cvt_bf16_kernel(const float* __restrict__ in, unsigned short* __restrict__ out, int n4) {
  const int i = blockIdx.x * 256 + threadIdx.x;
  if (i < n4) {
    float4 v = ((const float4*)in)[i];
    ushort4 o; o.x = f2bf(v.x); o.y = f2bf(v.y); o.z = f2bf(v.z); o.w = f2bf(v.w);
    ((ushort4*)out)[i] = o;
  }
}

// ====== GEMM v2: BM=256, BN=128, BK=64, 8 waves (4Mx2N), ring-3 LDS, ======
// ====== SOFTWARE-PIPELINED frag loads: ds_read(t+1) overlaps MFMA(t) ======
// __launch_bounds__(512, 1): block is 8 waves = 2 waves/SIMD -> 256 VGPR budget.
// (R10's (512,2) capped VGPR at 128 and spilled the frag sets to scratch:
//  WRITE_SIZE 65MB->313MB. This is the same kernel with the cap removed.)
template <int EPI>
__global__ __launch_bounds__(512, 1)
void gemm_r3(const ushort_t* __restrict__ A, const ushort_t* __restrict__ B,
             int K, int N,
             ushort_t* ob0, ushort_t* ob1, ushort_t* ob2, float* outf,
             const float* __restrict__ res, const float* __restrict__ bias,
             int nbx) {
  constexpr int SLOT = 49152;
  __shared__ __align__(16) char smem[3 * SLOT];

  const int tid = threadIdx.x;
  const int lane = tid & 63;
  const int wid = tid >> 6;
  const int wm = wid >> 1, wn = wid & 1;
  const int ln15 = lane & 15, g = lane >> 4;

  int wg = blockIdx.x;
  const int cpx = gridDim.x >> 3;
  wg = (wg & 7) * cpx + (wg >> 3);
  const int bx = wg % nbx, by = wg / nbx;
  const int m0 = by * 256, n0 = bx * 128;

  const char* Ab = (const char*)(A + (size_t)m0 * K);
  const char* Bb = (const char*)(B + (size_t)n0 * K);
  const size_t rowb = (size_t)K * 2;
  const int NT = K >> 6;            // always even (K multiple of 128)

  auto stage = [&](int t, int s) {
    char* As = smem + s * SLOT;
    char* Bs = As + 32768;
    const size_t kb = (size_t)t * 128;
    #pragma unroll
    for (int i = 0; i < 4; i++) {
      const int o = i * 8192 + tid * 16;
      const int row = o >> 7, col = o & 127;
      gload_lds16(Ab + (size_t)row * rowb + kb + (col ^ ((row & 7) << 4)), As + o);
    }
    #pragma unroll
    for (int i = 0; i < 2; i++) {
      const int o = i * 8192 + tid * 16;
      const int row = o >> 7, col = o & 127;
      gload_lds16(Bb + (size_t)row * rowb + kb + (col ^ ((row & 7) << 4)), Bs + o);
    }
  };

  f32x4 acc[4][4] = {};
  bf16x8 afA[4][2], bfA[4][2], afB[4][2], bfB[4][2];

  auto LD = [&](int s, bf16x8 (&af)[4][2], bf16x8 (&bf)[4][2]) {
    const char* As = smem + s * SLOT;
    const char* Bs = As + 32768;
    #pragma unroll
    for (int mi = 0; mi < 4; mi++) {
      const int row = wm * 64 + mi * 16 + ln15;
      #pragma unroll
      for (int kk = 0; kk < 2; kk++)
        af[mi][kk] = *(const bf16x8*)(As + row * 128 + ((kk * 64 + g * 16) ^ ((row & 7) << 4)));
    }
    #pragma unroll
    for (int ni = 0; ni < 4; ni++) {
      const int row = wn * 64 + ni * 16 + ln15;
      #pragma unroll
      for (int kk = 0; kk < 2; kk++)
        bf[ni][kk] = *(const bf16x8*)(Bs + row * 128 + ((kk * 64 + g * 16) ^ ((row & 7) << 4)));
    }
  };
  auto MM = [&](bf16x8 (&af)[4][2], bf16x8 (&bf)[4][2]) {
    __builtin_amdgcn_s_setprio(1);
    #pragma unroll
    for (int kk = 0; kk < 2; kk++)
      #pragma unroll
      for (int mi = 0; mi < 4; mi++)
        #pragma unroll
        for (int ni = 0; ni < 4; ni++)
          acc[mi][ni] = __builtin_amdgcn_mfma_f32_16x16x32_bf16(af[mi][kk], bf[ni][kk], acc[mi][ni], 0, 0, 0);
    __builtin_amdgcn_s_setprio(0);
  };

  stage(0, 0); stage(1, 1);
  waitvm<6>();
  __builtin_amdgcn_s_barrier();
  LD(0, afA, bfA);

  int slot = 0;                      // slot of tile t at loop top (t even)
  for (int t = 0; t < NT; t += 2) {
    // ---- even: compute t (set A), prefetch regs for t+1 (set B) ----
    {
      const int s2 = (slot + 2 >= 3) ? slot - 1 : slot + 2;
      if (t + 2 < NT) stage(t + 2, s2);
      if (t + 2 < NT) waitvm<6>(); else waitvm<0>();
      asm volatile("s_waitcnt lgkmcnt(0)" ::: "memory");
      __builtin_amdgcn_s_barrier();
      const int s1 = (slot + 1 >= 3) ? 0 : slot + 1;
      LD(s1, afB, bfB);                       // t+1 < NT always (NT even)
      __builtin_amdgcn_sched_barrier(0x7);    // MFMA may not hoist above; DS may not sink
      MM(afA, bfA);
    }
    // ---- odd: compute t+1 (set B), prefetch regs for t+2 (set A) ----
    {
      const int sB = (slot + 1 >= 3) ? 0 : slot + 1;   // slot of t+1
      const int s3 = (sB + 2 >= 3) ? sB - 1 : sB + 2;  // slot of t+3
      if (t + 3 < NT) stage(t + 3, s3);
      if (t + 3 < NT) waitvm<6>(); else waitvm<0>();
      asm volatile("s_waitcnt lgkmcnt(0)" ::: "memory");
      __builtin_amdgcn_s_barrier();
      if (t + 2 < NT) {
        const int s1 = (sB + 1 >= 3) ? 0 : sB + 1;
        LD(s1, afA, bfA);
        __builtin_amdgcn_sched_barrier(0x7);
        MM(afB, bfB);
      } else {
        MM(afB, bfB);
      }
    }
    slot = (slot + 2 >= 3) ? slot - 1 : slot + 2;
  }

  // ---------------- epilogue (from registers) ----------------
  #pragma unroll
  for (int mi = 0; mi < 4; mi++) {
    const int mrow = m0 + wm * 64 + mi * 16 + g * 4;
    #pragma unroll
    for (int ni = 0; ni < 4; ni++) {
      const int ncol = n0 + wn * 64 + ni * 16 + ln15;
      if (EPI == 0) {
        const int region = n0 >> 11;
        if (region == 0) {
          #pragma unroll
          for (int r = 0; r < 4; r++)
            ob0[(size_t)(mrow + r) * 2048 + ncol] = f2bf(acc[mi][ni][r]);
        } else if (region == 1) {
          #pragma unroll
          for (int r = 0; r < 4; r++)
            ob1[(size_t)(mrow + r) * 2048 + (ncol - 2048)] = f2bf(acc[mi][ni][r]);
        } else {
          const int bb = mrow >> 11, ss = mrow & 2047;
          const int ncv = ncol - 4096;
          const int hh = ncv >> 7, dd = ncv & 127;
          ushort4 v;
          v.x = f2bf(acc[mi][ni][0]); v.y = f2bf(acc[mi][ni][1]);
          v.z = f2bf(acc[mi][ni][2]); v.w = f2bf(acc[mi][ni][3]);
          *(ushort4*)(ob2 + ((size_t)((bb * 16 + hh) * 128 + dd)) * 2048 + ss) = v;
        }
      } else if (EPI == 2) {
        const float bv = bias[ncol];
        #pragma unroll
        for (int r = 0; r < 4; r++) {
          float v = acc[mi][ni][r] + bv;
          v = fminf(fmaxf(v, 0.0f), 6.0f);
          ob0[(size_t)(mrow + r) * N + ncol] = f2bf(v);
        }
      } else {
        const float bv = bias ? bias[ncol] : 0.0f;
        #pragma unroll
        for (int r = 0; r < 4; r++) {
          const size_t idx = (size_t)(mrow + r) * N + ncol;
          outf[idx] = res[idx] + acc[mi][ni][r] + bv;
        }
      }
    }
  }
}

// ------- Flash attention (causal), QBLK=128, KVBLK=64, 8 waves, 2 blocks/CU -------
__global__ __launch_bounds__(512, 2)
void attn_kernel(const unsigned short* __restrict__ Qg,
                 const unsigned short* __restrict__ Kg,
                 const unsigned short* __restrict__ Vg,
                 unsigned short* __restrict__ Og) {
  __shared__ __align__(16) char smem[65536];
  const int tid = threadIdx.x, lane = tid & 63, wid = tid >> 6;
  const int g = lane >> 4, qq = lane & 15;
  const int pairx = blockIdx.x, h = blockIdx.y, b = blockIdx.z;

  auto stage = [&](int kv0, char* kdst, char* vdst) {
    #pragma unroll
    for (int i = 0; i < 2; i++) {
      const int oo = i * 8192 + tid * 16;
      const int rK = oo >> 8;
      const int sK = (oo & 255) ^ ((rK & 7) << 4);
      gload_lds16((const char*)Kg + ((size_t)(b * 2048 + kv0 + rK) * 2048 + h * 128) * 2 + sK,
                  kdst + oo);
      const int rV = oo >> 7;
      const int sV = (oo & 127) ^ ((rV & 7) << 4);
      gload_lds16((const char*)Vg + ((size_t)((b * 16 + h) * 128 + rV) * 2048 + kv0) * 2 + sV,
                  vdst + oo);
    }
  };

  for (int half = 0; half < 2; ++half) {
    const int qb8 = half ? (15 - pairx) : pairx;
    const int q0 = qb8 * 128;
    const int myq = q0 + wid * 16 + qq;
    const int nt = 2 * qb8 + 2;

    bf16x8 qf[4];
    const unsigned short* qp = Qg + ((size_t)(b * 2048 + myq)) * 2048 + h * 128 + g * 8;
    #pragma unroll
    for (int ks = 0; ks < 4; ks++) qf[ks] = *(const bf16x8*)(qp + ks * 32);

    stage(0, smem, smem + 16384);

    float m_run = -1e30f, l_run = 0.0f;
    f32x4 oacc[8] = {};

    for (int t = 0; t < nt; ++t) {
      const int cur = t & 1;
      char* kbc = cur ? smem + 32768 : smem;
      char* vbc = cur ? smem + 49152 : smem + 16384;
      char* kbn = cur ? smem : smem + 32768;
      char* vbn = cur ? smem + 16384 : smem + 49152;

      if (t + 1 < nt) {
        stage((t + 1) * 64, kbn, vbn);
        asm volatile("s_waitcnt vmcnt(4)" ::: "memory");
      } else {
        asm volatile("s_waitcnt vmcnt(0)" ::: "memory");
      }
      __builtin_amdgcn_s_barrier();
      asm volatile("" ::: "memory");

      const int kv0 = t * 64;

      f32x4 st[4] = {};
      __builtin_amdgcn_s_setprio(1);
      #pragma unroll
      for (int ks = 0; ks < 4; ks++) {
        #pragma unroll
        for (int f = 0; f < 4; f++) {
          const int row = f * 16 + qq;
          const int cb = ks * 64 + g * 16;
          bf16x8 kf = *(const bf16x8*)(kbc + row * 256 + (cb ^ ((row & 7) << 4)));
          st[f] = __builtin_amdgcn_mfma_f32_16x16x32_bf16(kf, qf[ks], st[f], 0, 0, 0);
        }
      }
      __builtin_amdgcn_s_setprio(0);

      float p[4][4];
      float tmax = -3.0e38f;
      const bool diag = (kv0 + 63 > q0 + wid * 16);
      #pragma unroll
      for (int f = 0; f < 4; f++) {
        #pragma unroll
        for (int r = 0; r < 4; r++) {
          float v = st[f][r] * 0.08838834764831845f;
          if (diag) {
            const int kv = kv0 + f * 16 + g * 4 + r;
            if (kv > myq) v = -3.0e38f;
          }
          p[f][r] = v;
          tmax = fmaxf(tmax, v);
        }
      }
      tmax = fmaxf(tmax, __shfl_xor(tmax, 16));
      tmax = fmaxf(tmax, __shfl_xor(tmax, 32));
      const float m_new = fmaxf(m_run, tmax);
      const float sf = __expf(m_run - m_new);
      m_run = m_new;
      float tsum = 0.0f;
      #pragma unroll
      for (int f = 0; f < 4; f++) {
        #pragma unroll
        for (int r = 0; r < 4; r++) {
          p[f][r] = __expf(p[f][r] - m_new);
          tsum += p[f][r];
        }
      }
      tsum += __shfl_xor(tsum, 16);
      tsum += __shfl_xor(tsum, 32);
      l_run = l_run * sf + tsum;

      unsigned pk[4][2];
      #pragma unroll
      for (int f = 0; f < 4; f++) {
        pk[f][0] = (unsigned)f2bf(p[f][0]) | ((unsigned)f2bf(p[f][1]) << 16);
        pk[f][1] = (unsigned)f2bf(p[f][2]) | ((unsigned)f2bf(p[f][3]) << 16);
      }
      bf16x8 pa[2];
      const int sel = g >> 1;
      #pragma unroll
      for (int ks2 = 0; ks2 < 2; ks2++) {
        unsigned d[4];
        #pragma unroll
        for (int u = 0; u < 2; u++) {
          const int sl = qq + (((2 * g + u) & 3) << 4);
          const unsigned lo0 = (unsigned)__shfl((int)pk[2 * ks2][0], sl);
          const unsigned hi0 = (unsigned)__shfl((int)pk[2 * ks2 + 1][0], sl);
          const unsigned lo1 = (unsigned)__shfl((int)pk[2 * ks2][1], sl);
          const unsigned hi1 = (unsigned)__shfl((int)pk[2 * ks2 + 1][1], sl);
          d[2 * u]     = sel ? hi0 : lo0;
          d[2 * u + 1] = sel ? hi1 : lo1;
        }
        union { unsigned u[4]; bf16x8 v; } cv;
        cv.u[0] = d[0]; cv.u[1] = d[1]; cv.u[2] = d[2]; cv.u[3] = d[3];
        pa[ks2] = cv.v;
      }

      float sfr[4];
      #pragma unroll
      for (int r = 0; r < 4; r++) sfr[r] = __shfl(sf, g * 4 + r);
      #pragma unroll
      for (int nf = 0; nf < 8; nf++) {
        oacc[nf][0] *= sfr[0]; oacc[nf][1] *= sfr[1];
        oacc[nf][2] *= sfr[2]; oacc[nf][3] *= sfr[3];
      }
      __builtin_amdgcn_s_setprio(1);
      #pragma unroll
      for (int ks2 = 0; ks2 < 2; ks2++) {
        #pragma unroll
        for (int nf = 0; nf < 8; nf++) {
          const int row = nf * 16 + qq;
          const int cb = ks2 * 64 + g * 16;
          bf16x8 vf = *(const bf16x8*)(vbc + row * 128 + (cb ^ ((row & 7) << 4)));
          oacc[nf] = __builtin_amdgcn_mfma_f32_16x16x32_bf16(pa[ks2], vf, oacc[nf], 0, 0, 0);
        }
      }
      __builtin_amdgcn_s_setprio(0);

      asm volatile("" ::: "memory");
      __builtin_amdgcn_s_barrier();
    }

    asm volatile("" ::: "memory");
    const float inv = 1.0f / l_run;
    float invr[4];
    #pragma unroll
    for (int r = 0; r < 4; r++) invr[r] = __shfl(inv, g * 4 + r);

    float* Osm = (float*)smem;
    #pragma unroll
    for (int pass = 0; pass < 2; ++pass) {
      if ((wid >> 2) == pass) {
        const int w4 = wid & 3;
        #pragma unroll
        for (int nf = 0; nf < 8; nf++) {
          #pragma unroll
          for (int r = 0; r < 4; r++)
            Osm[(w4 * 16 + g * 4 + r) * 132 + nf * 16 + qq] = oacc[nf][r] * invr[r];
        }
      }
      __syncthreads();
      #pragma unroll
      for (int it = 0; it < 2; it++) {
        const int row = it * 32 + (tid >> 4);
        const int c0 = (tid & 15) * 8;
        const float* src = &Osm[row * 132 + c0];
        uint4 w;
        w.x = (unsigned)f2bf(src[0]) | ((unsigned)f2bf(src[1]) << 16);
        w.y = (unsigned)f2bf(src[2]) | ((unsigned)f2bf(src[3]) << 16);
        w.z = (unsigned)f2bf(src[4]) | ((unsigned)f2bf(src[5]) << 16);
        w.w = (unsigned)f2bf(src[6]) | ((unsigned)f2bf(src[7]) << 16);
        *(uint4*)(Og + (size_t)(b * 2048 + q0 + pass * 64 + row) * 2048 + h * 128 + c0) = w;
      }
      __syncthreads();
    }
  }
}

extern "C" void kernel_launch(void* const* d_in, const int* in_sizes, int n_in,
                              void* d_out, int out_size, void* d_ws, size_t ws_size,
                              hipStream_t stream) {
  (void)in_sizes; (void)n_in; (void)out_size; (void)ws_size;
  const float* x  = (const float*)d_in[0];
  const float* wq = (const float*)d_in[1];
  const float* wk = (const float*)d_in[2];
  const float* wv = (const float*)d_in[3];
  const float* wo = (const float*)d_in[4];
  const float* w1 = (const float*)d_in[5];
  const float* b1 = (const float*)d_in[6];
  const float* w2 = (const float*)d_in[7];
  const float* b2 = (const float*)d_in[8];
  float* out = (float*)d_out;
  char* ws = (char*)d_ws;

  // workspace layout (bytes); total = 184,549,376
  ushort_t* wqkvT = (ushort_t*)(ws + 0);            // [6144 n][2048 k] (q|k|v)
  ushort_t* wqT = wqkvT;
  ushort_t* wkT = (ushort_t*)(ws + 8388608);
  ushort_t* wvT = (ushort_t*)(ws + 16777216);
  ushort_t* woC = (ushort_t*)(ws + 25165824);       // [2048 e][2048 hk]
  ushort_t* w1T = (ushort_t*)(ws + 33554432);       // [8192 f][2048 e]
  ushort_t* w2T = (ushort_t*)(ws + 67108864);       // [2048 e][8192 f]
  ushort_t* h1  = (ushort_t*)(ws + 100663296);      // [4096][2048]
  ushort_t* Qb  = (ushort_t*)(ws + 117440512);
  ushort_t* Kb  = (ushort_t*)(ws + 134217728);
  ushort_t* Vt  = (ushort_t*)(ws + 150994944);      // [b,h,d,s]
  ushort_t* hid = h1;                                // [4096][8192] aliases h1/Q/K/V (dead)
  ushort_t* att = (ushort_t*)(ws + 167772160);
  ushort_t* h2  = att;                               // aliases att (dead then)

  const dim3 tb(32, 8);
  transpose_cvt<<<dim3(64, 64), tb, 0, stream>>>(wq, wqT, 2048, 2048);
  transpose_cvt<<<dim3(64, 64), tb, 0, stream>>>(wk, wkT, 2048, 2048);
  transpose_cvt<<<dim3(64, 64), tb, 0, stream>>>(wv, wvT, 2048, 2048);
  cvt_bf16_kernel<<<4096, 256, 0, stream>>>(wo, woC, 1048576);
  transpose_cvt<<<dim3(256, 64), tb, 0, stream>>>(w1, w1T, 2048, 8192);
  transpose_cvt<<<dim3(64, 256), tb, 0, stream>>>(w2, w2T, 8192, 2048);

  // h1 = rmsnorm(x)
  rmsnorm_kernel<<<4096, 256, 0, stream>>>(x, h1);
  // fused QKV (pipelined r3, 768 blocks = 3 exact rounds): Q->Qb, K->Kb, V->Vt
  gemm_r3<0><<<48 * 16, 512, 0, stream>>>(h1, wqkvT, 2048, 6144,
                                          Qb, Kb, Vt, nullptr, nullptr, nullptr, 48);
  // attention
  attn_kernel<<<dim3(8, 16, 2), 512, 0, stream>>>(Qb, Kb, Vt, att);
  // x1 = x + attn @ w_o -> d_out (fp32)
  gemm_r3<3><<<16 * 16, 512, 0, stream>>>(att, woC, 2048, 2048,
                                          nullptr, nullptr, nullptr, out, x, nullptr, 16);
  // h2 = rmsnorm(x1)
  rmsnorm_kernel<<<4096, 256, 0, stream>>>(out, h2);
  // hidden = relu6(h2 @ w1 + b1)  (pipelined r3, 1024 blocks = 4 exact rounds)
  gemm_r3<2><<<64 * 16, 512, 0, stream>>>(h2, w1T, 2048, 8192,
                                          hid, nullptr, nullptr, nullptr, nullptr, b1, 64);
  // out = x1 + hidden @ w2 + b2
  gemm_r3<3><<<16 * 16, 512, 0, stream>>>(hid, w2T, 8192, 2048,
                                          nullptr, nullptr, nullptr, out, out, b2, 16);
}

// Round 12
// 857.906 us; speedup vs baseline: 1.6881x; 1.6855x over previous
//
#include <hip/hip_runtime.h>
#include <hip/hip_bf16.h>
#include <stdint.h>

typedef __attribute__((ext_vector_type(8))) short bf16x8;
typedef __attribute__((ext_vector_type(4))) float f32x4;
typedef unsigned short ushort_t;

typedef __attribute__((address_space(1))) char as1_char;
typedef __attribute__((address_space(3))) char as3_char;

__device__ __forceinline__ void gload_lds16(const void* g, void* l) {
  __builtin_amdgcn_global_load_lds((as1_char*)g, (as3_char*)l, 16, 0, 0);
}

template <int N> __device__ __forceinline__ void waitvm() {
  asm volatile("s_waitcnt vmcnt(%0)" :: "n"(N) : "memory");
}

__device__ __forceinline__ unsigned short f2bf(float f) {
  union { float f; unsigned u; } c; c.f = f;
  unsigned u = c.u;
  return (unsigned short)((u + 0x7fffu + ((u >> 16) & 1u)) >> 16);
}

// ---------------- RMSNorm: fp32 [tok][2048] -> bf16 ----------------
__global__ __launch_bounds__(256)
void rmsnorm_kernel(const float* __restrict__ x, unsigned short* __restrict__ out) {
  const int tok = blockIdx.x;
  const int tid = threadIdx.x;
  const float4* xr = (const float4*)(x + (size_t)tok * 2048);
  float4 a = xr[tid];
  float4 b = xr[tid + 256];
  float s = a.x*a.x + a.y*a.y + a.z*a.z + a.w*a.w
          + b.x*b.x + b.y*b.y + b.z*b.z + b.w*b.w;
  #pragma unroll
  for (int m = 1; m < 64; m <<= 1) s += __shfl_xor(s, m);
  __shared__ float ws4[4];
  if ((tid & 63) == 0) ws4[tid >> 6] = s;
  __syncthreads();
  const float tot = ws4[0] + ws4[1] + ws4[2] + ws4[3];
  const float r = rsqrtf(tot * (1.0f / 2048.0f));
  ushort4 o1, o2;
  o1.x = f2bf(a.x * r); o1.y = f2bf(a.y * r); o1.z = f2bf(a.z * r); o1.w = f2bf(a.w * r);
  o2.x = f2bf(b.x * r); o2.y = f2bf(b.y * r); o2.z = f2bf(b.z * r); o2.w = f2bf(b.w * r);
  ushort4* orow = (ushort4*)(out + (size_t)tok * 2048);
  orow[tid] = o1;
  orow[tid + 256] = o2;
}

// ------------- transpose + convert: fp32 [R][C] -> bf16 [C][R] -------------
__global__ __launch_bounds__(256)
void transpose_cvt(const float* __restrict__ in, unsigned short* __restrict__ out,
                   int R, int C) {
  __shared__ float t[32][33];
  const int c0 = blockIdx.x * 32, r0 = blockIdx.y * 32;
  const int tx = threadIdx.x, ty = threadIdx.y;
  #pragma unroll
  for (int i = 0; i < 4; i++)
    t[ty + 8 * i][tx] = in[(size_t)(r0 + ty + 8 * i) * C + (c0 + tx)];
  __syncthreads();
  #pragma unroll
  for (int i = 0; i < 4; i++)
    out[(size_t)(c0 + ty + 8 * i) * R + (r0 + tx)] = f2bf(t[tx][ty + 8 * i]);
}

// ------------- convert only: fp32 -> bf16 (layout preserved) -------------
__global__ __launch_bounds__(256)
void cvt_bf16_kernel(const float* __restrict__ in, unsigned short* __restrict__ out, int n4) {
  const int i = blockIdx.x * 256 + threadIdx.x;
  if (i < n4) {
    float4 v = ((const float4*)in)[i];
    ushort4 o; o.x = f2bf(v.x); o.y = f2bf(v.y); o.z = f2bf(v.z); o.w = f2bf(v.w);
    ((ushort4*)out)[i] = o;
  }
}

// ====== GEMM (R8 known-good): BM=256, BN=128, BK=64, 8 waves, ring-3, 1 barrier/tile ======
template <int EPI>
__global__ __launch_bounds__(512, 1)
void gemm_r3(const ushort_t* __restrict__ A, const ushort_t* __restrict__ B,
             int K, int N,
             ushort_t* ob0, ushort_t* ob1, ushort_t* ob2, float* outf,
             const float* __restrict__ res, const float* __restrict__ bias,
             int nbx) {
  constexpr int SLOT = 49152;
  __shared__ __align__(16) char smem[3 * SLOT];

  const int tid = threadIdx.x;
  const int lane = tid & 63;
  const int wid = tid >> 6;
  const int wm = wid >> 1, wn = wid & 1;
  const int ln15 = lane & 15, g = lane >> 4;

  int wg = blockIdx.x;
  const int cpx = gridDim.x >> 3;
  wg = (wg & 7) * cpx + (wg >> 3);
  const int bx = wg % nbx, by = wg / nbx;
  const int m0 = by * 256, n0 = bx * 128;

  const char* Ab = (const char*)(A + (size_t)m0 * K);
  const char* Bb = (const char*)(B + (size_t)n0 * K);
  const size_t rowb = (size_t)K * 2;
  const int NT = K >> 6;

  auto stage = [&](int t, int slot) {
    char* As = smem + slot * SLOT;
    char* Bs = As + 32768;
    const size_t kb = (size_t)t * 128;
    #pragma unroll
    for (int i = 0; i < 4; i++) {
      const int o = i * 8192 + tid * 16;
      const int row = o >> 7, col = o & 127;
      gload_lds16(Ab + (size_t)row * rowb + kb + (col ^ ((row & 7) << 4)), As + o);
    }
    #pragma unroll
    for (int i = 0; i < 2; i++) {
      const int o = i * 8192 + tid * 16;
      const int row = o >> 7, col = o & 127;
      gload_lds16(Bb + (size_t)row * rowb + kb + (col ^ ((row & 7) << 4)), Bs + o);
    }
  };

  f32x4 acc[4][4] = {};

  stage(0, 0);
  if (NT > 1) stage(1, 1);

  int slot = 0;
  for (int t = 0; t < NT; ++t) {
    if (t + 1 < NT) waitvm<6>(); else waitvm<0>();
    __builtin_amdgcn_s_barrier();

    const int slot2 = (slot + 2 >= 3) ? slot - 1 : slot + 2;
    if (t + 2 < NT) stage(t + 2, slot2);

    const char* As = smem + slot * SLOT;
    const char* Bs = As + 32768;

    bf16x8 af[4][2], bfm[4][2];
    #pragma unroll
    for (int mi = 0; mi < 4; mi++) {
      const int row = wm * 64 + mi * 16 + ln15;
      #pragma unroll
      for (int kk = 0; kk < 2; kk++)
        af[mi][kk] = *(const bf16x8*)(As + row * 128 + ((kk * 64 + g * 16) ^ ((row & 7) << 4)));
    }
    #pragma unroll
    for (int ni = 0; ni < 4; ni++) {
      const int row = wn * 64 + ni * 16 + ln15;
      #pragma unroll
      for (int kk = 0; kk < 2; kk++)
        bfm[ni][kk] = *(const bf16x8*)(Bs + row * 128 + ((kk * 64 + g * 16) ^ ((row & 7) << 4)));
    }

    __builtin_amdgcn_s_setprio(1);
    #pragma unroll
    for (int kk = 0; kk < 2; kk++)
      #pragma unroll
      for (int mi = 0; mi < 4; mi++)
        #pragma unroll
        for (int ni = 0; ni < 4; ni++)
          acc[mi][ni] = __builtin_amdgcn_mfma_f32_16x16x32_bf16(af[mi][kk], bfm[ni][kk], acc[mi][ni], 0, 0, 0);
    __builtin_amdgcn_s_setprio(0);

    slot = (slot + 1 >= 3) ? 0 : slot + 1;
  }

  #pragma unroll
  for (int mi = 0; mi < 4; mi++) {
    const int mrow = m0 + wm * 64 + mi * 16 + g * 4;
    #pragma unroll
    for (int ni = 0; ni < 4; ni++) {
      const int ncol = n0 + wn * 64 + ni * 16 + ln15;
      if (EPI == 0) {
        const int region = n0 >> 11;
        if (region == 0) {
          #pragma unroll
          for (int r = 0; r < 4; r++)
            ob0[(size_t)(mrow + r) * 2048 + ncol] = f2bf(acc[mi][ni][r]);
        } else if (region == 1) {
          #pragma unroll
          for (int r = 0; r < 4; r++)
            ob1[(size_t)(mrow + r) * 2048 + (ncol - 2048)] = f2bf(acc[mi][ni][r]);
        } else {
          const int bb = mrow >> 11, ss = mrow & 2047;
          const int ncv = ncol - 4096;
          const int hh = ncv >> 7, dd = ncv & 127;
          ushort4 v;
          v.x = f2bf(acc[mi][ni][0]); v.y = f2bf(acc[mi][ni][1]);
          v.z = f2bf(acc[mi][ni][2]); v.w = f2bf(acc[mi][ni][3]);
          *(ushort4*)(ob2 + ((size_t)((bb * 16 + hh) * 128 + dd)) * 2048 + ss) = v;
        }
      } else if (EPI == 2) {
        const float bv = bias[ncol];
        #pragma unroll
        for (int r = 0; r < 4; r++) {
          float v = acc[mi][ni][r] + bv;
          v = fminf(fmaxf(v, 0.0f), 6.0f);
          ob0[(size_t)(mrow + r) * N + ncol] = f2bf(v);
        }
      } else {
        const float bv = bias ? bias[ncol] : 0.0f;
        #pragma unroll
        for (int r = 0; r < 4; r++) {
          const size_t idx = (size_t)(mrow + r) * N + ncol;
          outf[idx] = res[idx] + acc[mi][ni][r] + bv;
        }
      }
    }
  }
}

// ====== GEMM v3 (FFN1 only): pipelined frag loads, DE-SPILLED via named scalars ======
// 32 individually-named bf16x8 locals; macros (token pasting) — no arrays, no
// references, nothing address-taken -> SROA promotes to VGPRs (~200 live, fits
// 256-budget at 2 waves/SIMD). ds_read(t+1) frags issue before MFMA(t) cluster.
#define RDA(base, mi, kk) \
  (*(const bf16x8*)((base) + (wm * 64 + (mi) * 16 + ln15) * 128 + (((kk) * 64 + g * 16) ^ sw)))
#define RDB(base, ni, kk) \
  (*(const bf16x8*)((base) + (wn * 64 + (ni) * 16 + ln15) * 128 + (((kk) * 64 + g * 16) ^ sw)))
#define LDSET(S, X)                                                              \
  { const char* As_ = smem + (S) * SLOT; const char* Bs_ = As_ + 32768;          \
    a##X##0k0 = RDA(As_,0,0); a##X##0k1 = RDA(As_,0,1);                          \
    a##X##1k0 = RDA(As_,1,0); a##X##1k1 = RDA(As_,1,1);                          \
    a##X##2k0 = RDA(As_,2,0); a##X##2k1 = RDA(As_,2,1);                          \
    a##X##3k0 = RDA(As_,3,0); a##X##3k1 = RDA(As_,3,1);                          \
    b##X##0k0 = RDB(Bs_,0,0); b##X##0k1 = RDB(Bs_,0,1);                          \
    b##X##1k0 = RDB(Bs_,1,0); b##X##1k1 = RDB(Bs_,1,1);                          \
    b##X##2k0 = RDB(Bs_,2,0); b##X##2k1 = RDB(Bs_,2,1);                          \
    b##X##3k0 = RDB(Bs_,3,0); b##X##3k1 = RDB(Bs_,3,1); }
#define MF1(m, n, a, b) acc[m][n] = __builtin_amdgcn_mfma_f32_16x16x32_bf16(a, b, acc[m][n], 0, 0, 0)
#define MMSET(X)                                                                 \
  __builtin_amdgcn_s_setprio(1);                                                 \
  MF1(0,0,a##X##0k0,b##X##0k0); MF1(0,1,a##X##0k0,b##X##1k0);                    \
  MF1(0,2,a##X##0k0,b##X##2k0); MF1(0,3,a##X##0k0,b##X##3k0);                    \
  MF1(1,0,a##X##1k0,b##X##0k0); MF1(1,1,a##X##1k0,b##X##1k0);                    \
  MF1(1,2,a##X##1k0,b##X##2k0); MF1(1,3,a##X##1k0,b##X##3k0);                    \
  MF1(2,0,a##X##2k0,b##X##0k0); MF1(2,1,a##X##2k0,b##X##1k0);                    \
  MF1(2,2,a##X##2k0,b##X##2k0); MF1(2,3,a##X##2k0,b##X##3k0);                    \
  MF1(3,0,a##X##3k0,b##X##0k0); MF1(3,1,a##X##3k0,b##X##1k0);                    \
  MF1(3,2,a##X##3k0,b##X##2k0); MF1(3,3,a##X##3k0,b##X##3k0);                    \
  MF1(0,0,a##X##0k1,b##X##0k1); MF1(0,1,a##X##0k1,b##X##1k1);                    \
  MF1(0,2,a##X##0k1,b##X##2k1); MF1(0,3,a##X##0k1,b##X##3k1);                    \
  MF1(1,0,a##X##1k1,b##X##0k1); MF1(1,1,a##X##1k1,b##X##1k1);                    \
  MF1(1,2,a##X##1k1,b##X##2k1); MF1(1,3,a##X##1k1,b##X##3k1);                    \
  MF1(2,0,a##X##2k1,b##X##0k1); MF1(2,1,a##X##2k1,b##X##1k1);                    \
  MF1(2,2,a##X##2k1,b##X##2k1); MF1(2,3,a##X##2k1,b##X##3k1);                    \
  MF1(3,0,a##X##3k1,b##X##0k1); MF1(3,1,a##X##3k1,b##X##1k1);                    \
  MF1(3,2,a##X##3k1,b##X##2k1); MF1(3,3,a##X##3k1,b##X##3k1);                    \
  __builtin_amdgcn_s_setprio(0);

__global__ __launch_bounds__(512, 1)
void gemm_p2(const ushort_t* __restrict__ A, const ushort_t* __restrict__ B,
             int K, int N, ushort_t* ob0, const float* __restrict__ bias, int nbx) {
  constexpr int SLOT = 49152;
  __shared__ __align__(16) char smem[3 * SLOT];

  const int tid = threadIdx.x;
  const int lane = tid & 63;
  const int wid = tid >> 6;
  const int wm = wid >> 1, wn = wid & 1;
  const int ln15 = lane & 15, g = lane >> 4;
  const int sw = (ln15 & 7) << 4;            // XOR swizzle term (row&7)<<4

  int wg = blockIdx.x;
  const int cpx = gridDim.x >> 3;
  wg = (wg & 7) * cpx + (wg >> 3);
  const int bx = wg % nbx, by = wg / nbx;
  const int m0 = by * 256, n0 = bx * 128;

  const char* Ab = (const char*)(A + (size_t)m0 * K);
  const char* Bb = (const char*)(B + (size_t)n0 * K);
  const size_t rowb = (size_t)K * 2;
  const int NT = K >> 6;                      // even (K multiple of 128)

  auto stage = [&](int t, int s) {
    char* As = smem + s * SLOT;
    char* Bs = As + 32768;
    const size_t kb = (size_t)t * 128;
    #pragma unroll
    for (int i = 0; i < 4; i++) {
      const int o = i * 8192 + tid * 16;
      const int row = o >> 7, col = o & 127;
      gload_lds16(Ab + (size_t)row * rowb + kb + (col ^ ((row & 7) << 4)), As + o);
    }
    #pragma unroll
    for (int i = 0; i < 2; i++) {
      const int o = i * 8192 + tid * 16;
      const int row = o >> 7, col = o & 127;
      gload_lds16(Bb + (size_t)row * rowb + kb + (col ^ ((row & 7) << 4)), Bs + o);
    }
  };

  f32x4 acc[4][4] = {};
  bf16x8 aA0k0, aA0k1, aA1k0, aA1k1, aA2k0, aA2k1, aA3k0, aA3k1;
  bf16x8 bA0k0, bA0k1, bA1k0, bA1k1, bA2k0, bA2k1, bA3k0, bA3k1;
  bf16x8 aB0k0, aB0k1, aB1k0, aB1k1, aB2k0, aB2k1, aB3k0, aB3k1;
  bf16x8 bB0k0, bB0k1, bB1k0, bB1k1, bB2k0, bB2k1, bB3k0, bB3k1;

  stage(0, 0); stage(1, 1);
  waitvm<6>();
  __builtin_amdgcn_s_barrier();
  LDSET(0, A)

  int slot = 0;                               // slot of tile t at loop top (t even)
  for (int t = 0; t < NT; t += 2) {
    // ---- even: compute t (set A), frag-prefetch t+1 (set B) ----
    {
      const int s2 = (slot + 2 >= 3) ? slot - 1 : slot + 2;
      if (t + 2 < NT) stage(t + 2, s2);
      if (t + 2 < NT) waitvm<6>(); else waitvm<0>();
      asm volatile("s_waitcnt lgkmcnt(0)" ::: "memory");
      __builtin_amdgcn_s_barrier();
      const int s1 = (slot + 1 >= 3) ? 0 : slot + 1;
      LDSET(s1, B)
      __builtin_amdgcn_sched_barrier(0x7);
      MMSET(A)
    }
    // ---- odd: compute t+1 (set B), frag-prefetch t+2 (set A) ----
    {
      const int sB = (slot + 1 >= 3) ? 0 : slot + 1;
      const int s3 = (sB + 2 >= 3) ? sB - 1 : sB + 2;
      if (t + 3 < NT) stage(t + 3, s3);
      if (t + 3 < NT) waitvm<6>(); else waitvm<0>();
      asm volatile("s_waitcnt lgkmcnt(0)" ::: "memory");
      __builtin_amdgcn_s_barrier();
      if (t + 2 < NT) {
        const int s1 = (sB + 1 >= 3) ? 0 : sB + 1;
        LDSET(s1, A)
        __builtin_amdgcn_sched_barrier(0x7);
        MMSET(B)
      } else {
        MMSET(B)
      }
    }
    slot = (slot + 2 >= 3) ? slot - 1 : slot + 2;
  }

  // epilogue: +bias, ReLU6, bf16
  #pragma unroll
  for (int mi = 0; mi < 4; mi++) {
    const int mrow = m0 + wm * 64 + mi * 16 + g * 4;
    #pragma unroll
    for (int ni = 0; ni < 4; ni++) {
      const int ncol = n0 + wn * 64 + ni * 16 + ln15;
      const float bv = bias[ncol];
      #pragma unroll
      for (int r = 0; r < 4; r++) {
        float v = acc[mi][ni][r] + bv;
        v = fminf(fmaxf(v, 0.0f), 6.0f);
        ob0[(size_t)(mrow + r) * N + ncol] = f2bf(v);
      }
    }
  }
}
#undef RDA
#undef RDB
#undef LDSET
#undef MF1
#undef MMSET

// ------- Flash attention (causal), QBLK=128, KVBLK=64, 8 waves, 2 blocks/CU -------
__global__ __launch_bounds__(512, 2)
void attn_kernel(const unsigned short* __restrict__ Qg,
                 const unsigned short* __restrict__ Kg,
                 const unsigned short* __restrict__ Vg,
                 unsigned short* __restrict__ Og) {
  __shared__ __align__(16) char smem[65536];
  const int tid = threadIdx.x, lane = tid & 63, wid = tid >> 6;
  const int g = lane >> 4, qq = lane & 15;
  const int pairx = blockIdx.x, h = blockIdx.y, b = blockIdx.z;

  auto stage = [&](int kv0, char* kdst, char* vdst) {
    #pragma unroll
    for (int i = 0; i < 2; i++) {
      const int oo = i * 8192 + tid * 16;
      const int rK = oo >> 8;
      const int sK = (oo & 255) ^ ((rK & 7) << 4);
      gload_lds16((const char*)Kg + ((size_t)(b * 2048 + kv0 + rK) * 2048 + h * 128) * 2 + sK,
                  kdst + oo);
      const int rV = oo >> 7;
      const int sV = (oo & 127) ^ ((rV & 7) << 4);
      gload_lds16((const char*)Vg + ((size_t)((b * 16 + h) * 128 + rV) * 2048 + kv0) * 2 + sV,
                  vdst + oo);
    }
  };

  for (int half = 0; half < 2; ++half) {
    const int qb8 = half ? (15 - pairx) : pairx;
    const int q0 = qb8 * 128;
    const int myq = q0 + wid * 16 + qq;
    const int nt = 2 * qb8 + 2;

    bf16x8 qf[4];
    const unsigned short* qp = Qg + ((size_t)(b * 2048 + myq)) * 2048 + h * 128 + g * 8;
    #pragma unroll
    for (int ks = 0; ks < 4; ks++) qf[ks] = *(const bf16x8*)(qp + ks * 32);

    stage(0, smem, smem + 16384);

    float m_run = -1e30f, l_run = 0.0f;
    f32x4 oacc[8] = {};

    for (int t = 0; t < nt; ++t) {
      const int cur = t & 1;
      char* kbc = cur ? smem + 32768 : smem;
      char* vbc = cur ? smem + 49152 : smem + 16384;
      char* kbn = cur ? smem : smem + 32768;
      char* vbn = cur ? smem + 16384 : smem + 49152;

      if (t + 1 < nt) {
        stage((t + 1) * 64, kbn, vbn);
        asm volatile("s_waitcnt vmcnt(4)" ::: "memory");
      } else {
        asm volatile("s_waitcnt vmcnt(0)" ::: "memory");
      }
      __builtin_amdgcn_s_barrier();
      asm volatile("" ::: "memory");

      const int kv0 = t * 64;

      f32x4 st[4] = {};
      __builtin_amdgcn_s_setprio(1);
      #pragma unroll
      for (int ks = 0; ks < 4; ks++) {
        #pragma unroll
        for (int f = 0; f < 4; f++) {
          const int row = f * 16 + qq;
          const int cb = ks * 64 + g * 16;
          bf16x8 kf = *(const bf16x8*)(kbc + row * 256 + (cb ^ ((row & 7) << 4)));
          st[f] = __builtin_amdgcn_mfma_f32_16x16x32_bf16(kf, qf[ks], st[f], 0, 0, 0);
        }
      }
      __builtin_amdgcn_s_setprio(0);

      float p[4][4];
      float tmax = -3.0e38f;
      const bool diag = (kv0 + 63 > q0 + wid * 16);
      #pragma unroll
      for (int f = 0; f < 4; f++) {
        #pragma unroll
        for (int r = 0; r < 4; r++) {
          float v = st[f][r] * 0.08838834764831845f;
          if (diag) {
            const int kv = kv0 + f * 16 + g * 4 + r;
            if (kv > myq) v = -3.0e38f;
          }
          p[f][r] = v;
          tmax = fmaxf(tmax, v);
        }
      }
      tmax = fmaxf(tmax, __shfl_xor(tmax, 16));
      tmax = fmaxf(tmax, __shfl_xor(tmax, 32));
      const float m_new = fmaxf(m_run, tmax);
      const float sf = __expf(m_run - m_new);
      m_run = m_new;
      float tsum = 0.0f;
      #pragma unroll
      for (int f = 0; f < 4; f++) {
        #pragma unroll
        for (int r = 0; r < 4; r++) {
          p[f][r] = __expf(p[f][r] - m_new);
          tsum += p[f][r];
        }
      }
      tsum += __shfl_xor(tsum, 16);
      tsum += __shfl_xor(tsum, 32);
      l_run = l_run * sf + tsum;

      unsigned pk[4][2];
      #pragma unroll
      for (int f = 0; f < 4; f++) {
        pk[f][0] = (unsigned)f2bf(p[f][0]) | ((unsigned)f2bf(p[f][1]) << 16);
        pk[f][1] = (unsigned)f2bf(p[f][2]) | ((unsigned)f2bf(p[f][3]) << 16);
      }
      bf16x8 pa[2];
      const int sel = g >> 1;
      #pragma unroll
      for (int ks2 = 0; ks2 < 2; ks2++) {
        unsigned d[4];
        #pragma unroll
        for (int u = 0; u < 2; u++) {
          const int sl = qq + (((2 * g + u) & 3) << 4);
          const unsigned lo0 = (unsigned)__shfl((int)pk[2 * ks2][0], sl);
          const unsigned hi0 = (unsigned)__shfl((int)pk[2 * ks2 + 1][0], sl);
          const unsigned lo1 = (unsigned)__shfl((int)pk[2 * ks2][1], sl);
          const unsigned hi1 = (unsigned)__shfl((int)pk[2 * ks2 + 1][1], sl);
          d[2 * u]     = sel ? hi0 : lo0;
          d[2 * u + 1] = sel ? hi1 : lo1;
        }
        union { unsigned u[4]; bf16x8 v; } cv;
        cv.u[0] = d[0]; cv.u[1] = d[1]; cv.u[2] = d[2]; cv.u[3] = d[3];
        pa[ks2] = cv.v;
      }

      float sfr[4];
      #pragma unroll
      for (int r = 0; r < 4; r++) sfr[r] = __shfl(sf, g * 4 + r);
      #pragma unroll
      for (int nf = 0; nf < 8; nf++) {
        oacc[nf][0] *= sfr[0]; oacc[nf][1] *= sfr[1];
        oacc[nf][2] *= sfr[2]; oacc[nf][3] *= sfr[3];
      }
      __builtin_amdgcn_s_setprio(1);
      #pragma unroll
      for (int ks2 = 0; ks2 < 2; ks2++) {
        #pragma unroll
        for (int nf = 0; nf < 8; nf++) {
          const int row = nf * 16 + qq;
          const int cb = ks2 * 64 + g * 16;
          bf16x8 vf = *(const bf16x8*)(vbc + row * 128 + (cb ^ ((row & 7) << 4)));
          oacc[nf] = __builtin_amdgcn_mfma_f32_16x16x32_bf16(pa[ks2], vf, oacc[nf], 0, 0, 0);
        }
      }
      __builtin_amdgcn_s_setprio(0);

      asm volatile("" ::: "memory");
      __builtin_amdgcn_s_barrier();
    }

    asm volatile("" ::: "memory");
    const float inv = 1.0f / l_run;
    float invr[4];
    #pragma unroll
    for (int r = 0; r < 4; r++) invr[r] = __shfl(inv, g * 4 + r);

    float* Osm = (float*)smem;
    #pragma unroll
    for (int pass = 0; pass < 2; ++pass) {
      if ((wid >> 2) == pass) {
        const int w4 = wid & 3;
        #pragma unroll
        for (int nf = 0; nf < 8; nf++) {
          #pragma unroll
          for (int r = 0; r < 4; r++)
            Osm[(w4 * 16 + g * 4 + r) * 132 + nf * 16 + qq] = oacc[nf][r] * invr[r];
        }
      }
      __syncthreads();
      #pragma unroll
      for (int it = 0; it < 2; it++) {
        const int row = it * 32 + (tid >> 4);
        const int c0 = (tid & 15) * 8;
        const float* src = &Osm[row * 132 + c0];
        uint4 w;
        w.x = (unsigned)f2bf(src[0]) | ((unsigned)f2bf(src[1]) << 16);
        w.y = (unsigned)f2bf(src[2]) | ((unsigned)f2bf(src[3]) << 16);
        w.z = (unsigned)f2bf(src[4]) | ((unsigned)f2bf(src[5]) << 16);
        w.w = (unsigned)f2bf(src[6]) | ((unsigned)f2bf(src[7]) << 16);
        *(uint4*)(Og + (size_t)(b * 2048 + q0 + pass * 64 + row) * 2048 + h * 128 + c0) = w;
      }
      __syncthreads();
    }
  }
}

extern "C" void kernel_launch(void* const* d_in, const int* in_sizes, int n_in,
                              void* d_out, int out_size, void* d_ws, size_t ws_size,
                              hipStream_t stream) {
  (void)in_sizes; (void)n_in; (void)out_size; (void)ws_size;
  const float* x  = (const float*)d_in[0];
  const float* wq = (const float*)d_in[1];
  const float* wk = (const float*)d_in[2];
  const float* wv = (const float*)d_in[3];
  const float* wo = (const float*)d_in[4];
  const float* w1 = (const float*)d_in[5];
  const float* b1 = (const float*)d_in[6];
  const float* w2 = (const float*)d_in[7];
  const float* b2 = (const float*)d_in[8];
  float* out = (float*)d_out;
  char* ws = (char*)d_ws;

  // workspace layout (bytes); total = 184,549,376
  ushort_t* wqkvT = (ushort_t*)(ws + 0);            // [6144 n][2048 k] (q|k|v)
  ushort_t* wqT = wqkvT;
  ushort_t* wkT = (ushort_t*)(ws + 8388608);
  ushort_t* wvT = (ushort_t*)(ws + 16777216);
  ushort_t* woC = (ushort_t*)(ws + 25165824);       // [2048 e][2048 hk]
  ushort_t* w1T = (ushort_t*)(ws + 33554432);       // [8192 f][2048 e]
  ushort_t* w2T = (ushort_t*)(ws + 67108864);       // [2048 e][8192 f]
  ushort_t* h1  = (ushort_t*)(ws + 100663296);      // [4096][2048]
  ushort_t* Qb  = (ushort_t*)(ws + 117440512);
  ushort_t* Kb  = (ushort_t*)(ws + 134217728);
  ushort_t* Vt  = (ushort_t*)(ws + 150994944);      // [b,h,d,s]
  ushort_t* hid = h1;                                // [4096][8192] aliases h1/Q/K/V (dead)
  ushort_t* att = (ushort_t*)(ws + 167772160);
  ushort_t* h2  = att;                               // aliases att (dead then)

  const dim3 tb(32, 8);
  transpose_cvt<<<dim3(64, 64), tb, 0, stream>>>(wq, wqT, 2048, 2048);
  transpose_cvt<<<dim3(64, 64), tb, 0, stream>>>(wk, wkT, 2048, 2048);
  transpose_cvt<<<dim3(64, 64), tb, 0, stream>>>(wv, wvT, 2048, 2048);
  cvt_bf16_kernel<<<4096, 256, 0, stream>>>(wo, woC, 1048576);
  transpose_cvt<<<dim3(256, 64), tb, 0, stream>>>(w1, w1T, 2048, 8192);
  transpose_cvt<<<dim3(64, 256), tb, 0, stream>>>(w2, w2T, 8192, 2048);

  // h1 = rmsnorm(x)
  rmsnorm_kernel<<<4096, 256, 0, stream>>>(x, h1);
  // fused QKV (known-good r3): Q->Qb, K->Kb, V->Vt
  gemm_r3<0><<<48 * 16, 512, 0, stream>>>(h1, wqkvT, 2048, 6144,
                                          Qb, Kb, Vt, nullptr, nullptr, nullptr, 48);
  // attention
  attn_kernel<<<dim3(8, 16, 2), 512, 0, stream>>>(Qb, Kb, Vt, att);
  // x1 = x + attn @ w_o -> d_out (fp32)
  gemm_r3<3><<<16 * 16, 512, 0, stream>>>(att, woC, 2048, 2048,
                                          nullptr, nullptr, nullptr, out, x, nullptr, 16);
  // h2 = rmsnorm(x1)
  rmsnorm_kernel<<<4096, 256, 0, stream>>>(out, h2);
  // hidden = relu6(h2 @ w1 + b1)  (PIPELINED v3, de-spilled)
  gemm_p2<<<64 * 16, 512, 0, stream>>>(h2, w1T, 2048, 8192, hid, b1, 64);
  // out = x1 + hidden @ w2 + b2
  gemm_r3<3><<<16 * 16, 512, 0, stream>>>(hid, w2T, 8192, 2048,
                                          nullptr, nullptr, nullptr, out, out, b2, 16);
}

// Round 13
// 584.805 us; speedup vs baseline: 2.4764x; 1.4670x over previous
//
#include <hip/hip_runtime.h>
#include <hip/hip_bf16.h>
#include <stdint.h>

typedef __attribute__((ext_vector_type(8))) short bf16x8;
typedef __attribute__((ext_vector_type(4))) float f32x4;
typedef unsigned short ushort_t;

typedef __attribute__((address_space(1))) char as1_char;
typedef __attribute__((address_space(3))) char as3_char;

__device__ __forceinline__ void gload_lds16(const void* g, void* l) {
  __builtin_amdgcn_global_load_lds((as1_char*)g, (as3_char*)l, 16, 0, 0);
}

template <int N> __device__ __forceinline__ void waitvm() {
  asm volatile("s_waitcnt vmcnt(%0)" :: "n"(N) : "memory");
}

__device__ __forceinline__ unsigned short f2bf(float f) {
  union { float f; unsigned u; } c; c.f = f;
  unsigned u = c.u;
  return (unsigned short)((u + 0x7fffu + ((u >> 16) & 1u)) >> 16);
}

// ---------------- RMSNorm: fp32 [tok][2048] -> bf16 ----------------
__global__ __launch_bounds__(256)
void rmsnorm_kernel(const float* __restrict__ x, unsigned short* __restrict__ out) {
  const int tok = blockIdx.x;
  const int tid = threadIdx.x;
  const float4* xr = (const float4*)(x + (size_t)tok * 2048);
  float4 a = xr[tid];
  float4 b = xr[tid + 256];
  float s = a.x*a.x + a.y*a.y + a.z*a.z + a.w*a.w
          + b.x*b.x + b.y*b.y + b.z*b.z + b.w*b.w;
  #pragma unroll
  for (int m = 1; m < 64; m <<= 1) s += __shfl_xor(s, m);
  __shared__ float ws4[4];
  if ((tid & 63) == 0) ws4[tid >> 6] = s;
  __syncthreads();
  const float tot = ws4[0] + ws4[1] + ws4[2] + ws4[3];
  const float r = rsqrtf(tot * (1.0f / 2048.0f));
  ushort4 o1, o2;
  o1.x = f2bf(a.x * r); o1.y = f2bf(a.y * r); o1.z = f2bf(a.z * r); o1.w = f2bf(a.w * r);
  o2.x = f2bf(b.x * r); o2.y = f2bf(b.y * r); o2.z = f2bf(b.z * r); o2.w = f2bf(b.w * r);
  ushort4* orow = (ushort4*)(out + (size_t)tok * 2048);
  orow[tid] = o1;
  orow[tid + 256] = o2;
}

// ------------- transpose + convert: fp32 [R][C] -> bf16 [C][R] -------------
__global__ __launch_bounds__(256)
void transpose_cvt(const float* __restrict__ in, unsigned short* __restrict__ out,
                   int R, int C) {
  __shared__ float t[32][33];
  const int c0 = blockIdx.x * 32, r0 = blockIdx.y * 32;
  const int tx = threadIdx.x, ty = threadIdx.y;
  #pragma unroll
  for (int i = 0; i < 4; i++)
    t[ty + 8 * i][tx] = in[(size_t)(r0 + ty + 8 * i) * C + (c0 + tx)];
  __syncthreads();
  #pragma unroll
  for (int i = 0; i < 4; i++)
    out[(size_t)(c0 + ty + 8 * i) * R + (r0 + tx)] = f2bf(t[tx][ty + 8 * i]);
}

// ---- fused QKV weight transpose: z selects wq/wk/wv; out slices of [6144][2048] ----
__global__ __launch_bounds__(256)
void transpose_cvt3(const float* __restrict__ w0, const float* __restrict__ w1,
                    const float* __restrict__ w2, unsigned short* __restrict__ out) {
  __shared__ float t[32][33];
  const float* in = (blockIdx.z == 0) ? w0 : (blockIdx.z == 1) ? w1 : w2;
  unsigned short* o = out + (size_t)blockIdx.z * 2048 * 2048;
  const int c0 = blockIdx.x * 32, r0 = blockIdx.y * 32;
  const int tx = threadIdx.x, ty = threadIdx.y;
  #pragma unroll
  for (int i = 0; i < 4; i++)
    t[ty + 8 * i][tx] = in[(size_t)(r0 + ty + 8 * i) * 2048 + (c0 + tx)];
  __syncthreads();
  #pragma unroll
  for (int i = 0; i < 4; i++)
    o[(size_t)(c0 + ty + 8 * i) * 2048 + (r0 + tx)] = f2bf(t[tx][ty + 8 * i]);
}

// ------------- convert only: fp32 -> bf16 (layout preserved) -------------
__global__ __launch_bounds__(256)
void cvt_bf16_kernel(const float* __restrict__ in, unsigned short* __restrict__ out, int n4) {
  const int i = blockIdx.x * 256 + threadIdx.x;
  if (i < n4) {
    float4 v = ((const float4*)in)[i];
    ushort4 o; o.x = f2bf(v.x); o.y = f2bf(v.y); o.z = f2bf(v.z); o.w = f2bf(v.w);
    ((ushort4*)out)[i] = o;
  }
}

// ============== 256x256 8-phase GEMM, 8 waves (2Mx4N) — R9 known-good ==============
template <int EPI>
__global__ __launch_bounds__(512, 1)
void gemm8p(const ushort_t* __restrict__ A, const ushort_t* __restrict__ B,
            int K, int N,
            ushort_t* ob0, ushort_t* ob1, ushort_t* ob2,
            const float* __restrict__ bias, int nbx) {
  __shared__ __align__(16) char smem[131072];
  const int tid = threadIdx.x;
  const int lane = tid & 63;
  const int wid = tid >> 6;
  const int wm = wid >> 2, wn = wid & 3;     // 2M x 4N; wave out 128x64
  const int ln15 = lane & 15, g = lane >> 4;

  int wg = blockIdx.x;
  const int cpx = gridDim.x >> 3;
  wg = (wg & 7) * cpx + (wg >> 3);
  const int bx = wg % nbx, by = wg / nbx;
  const int m0 = by * 256, n0 = bx * 256;

  const char* Ab = (const char*)(A + (size_t)m0 * K);
  const char* Bb = (const char*)(B + (size_t)n0 * K);
  const size_t rowb = (size_t)K * 2;
  const int ITERS = K >> 7;                  // 2 K-tiles (of 64) per iter

  auto stA = [&](int t, int h) {
    char* dst = smem + ((t & 1) << 16) + (h << 14);
    const size_t kb = (size_t)t << 7;
    #pragma unroll
    for (int j = 0; j < 2; j++) {
      const int o = j * 8192 + tid * 16;
      const int lr = o >> 7, col = o & 127;
      const int grow = (lr & 63) + (h << 6) + ((lr >> 6) << 7);
      gload_lds16(Ab + (size_t)grow * rowb + kb + (col ^ ((lr & 7) << 4)), dst + o);
    }
  };
  auto stB = [&](int t, int h) {
    char* dst = smem + ((t & 1) << 16) + 32768 + (h << 14);
    const size_t kb = (size_t)t << 7;
    #pragma unroll
    for (int j = 0; j < 2; j++) {
      const int o = j * 8192 + tid * 16;
      const int lr = o >> 7, col = o & 127;
      const int grow = (lr & 31) + (h << 5) + ((lr >> 5) << 6);
      gload_lds16(Bb + (size_t)grow * rowb + kb + (col ^ ((lr & 7) << 4)), dst + o);
    }
  };

  f32x4 acc[8][4] = {};
  bf16x8 af[8], bfr[4];
  const int lra = wm * 64 + ln15;
  const int lrb = wn * 32 + ln15;

  auto ldA = [&](int c, int mh) {
    const char* base = smem + (c << 16) + (mh << 14);
    #pragma unroll
    for (int mi = 0; mi < 4; mi++) {
      const int lr = lra + mi * 16;
      #pragma unroll
      for (int kk = 0; kk < 2; kk++)
        af[mi * 2 + kk] = *(const bf16x8*)(base + lr * 128 + ((kk * 64 + g * 16) ^ ((lr & 7) << 4)));
    }
  };
  auto ldB = [&](int c, int nh) {
    const char* base = smem + (c << 16) + 32768 + (nh << 14);
    #pragma unroll
    for (int ni = 0; ni < 2; ni++) {
      const int lr = lrb + ni * 16;
      #pragma unroll
      for (int kk = 0; kk < 2; kk++)
        bfr[ni * 2 + kk] = *(const bf16x8*)(base + lr * 128 + ((kk * 64 + g * 16) ^ ((lr & 7) << 4)));
    }
  };

#define MFQ(MH, NH)                                                              \
  __builtin_amdgcn_s_barrier();                                                  \
  __builtin_amdgcn_s_setprio(1);                                                 \
  _Pragma("unroll")                                                              \
  for (int kk = 0; kk < 2; kk++)                                                 \
    _Pragma("unroll")                                                            \
    for (int mi = 0; mi < 4; mi++)                                               \
      _Pragma("unroll")                                                          \
      for (int ni = 0; ni < 2; ni++)                                             \
        acc[(MH) * 4 + mi][(NH) * 2 + ni] = __builtin_amdgcn_mfma_f32_16x16x32_bf16( \
            af[mi * 2 + kk], bfr[ni * 2 + kk], acc[(MH) * 4 + mi][(NH) * 2 + ni], 0, 0, 0); \
  __builtin_amdgcn_s_setprio(0);                                                 \
  __builtin_amdgcn_s_barrier();

  // prologue
  stA(0, 0); stB(0, 0); stB(0, 1); stA(0, 1);
  stA(1, 0); stB(1, 1); stA(1, 1);
  waitvm<6>();
  __builtin_amdgcn_s_barrier();

  for (int i = 0; i < ITERS; ++i) {
    const int a = 2 * i, b = a + 1;
    const bool pf = (i + 1 < ITERS);
    // ---- tile a (buf0) ----
    ldA(0, 0); ldB(0, 0); stB(b, 0);
    MFQ(0, 0)
    ldB(0, 1); if (pf) stA(a + 2, 0);
    MFQ(0, 1)
    ldA(0, 1); if (pf) stB(a + 2, 1);
    MFQ(1, 1)
    ldB(0, 0); if (pf) stA(a + 2, 1);
    if (pf) waitvm<6>(); else waitvm<0>();
    MFQ(1, 0)
    // ---- tile b (buf1) ----
    ldA(1, 0); ldB(1, 0); if (pf) stB(a + 2, 0);
    MFQ(0, 0)
    ldB(1, 1); if (pf) stA(b + 2, 0);
    MFQ(0, 1)
    ldA(1, 1); if (pf) stB(b + 2, 1);
    MFQ(1, 1)
    ldB(1, 0); if (pf) stA(b + 2, 1);
    if (pf) waitvm<6>();
    MFQ(1, 0)
  }
#undef MFQ

  #pragma unroll
  for (int mig = 0; mig < 8; mig++) {
    const int mrow = m0 + wm * 128 + (mig >> 2) * 64 + (mig & 3) * 16 + g * 4;
    #pragma unroll
    for (int nig = 0; nig < 4; nig++) {
      const int ncol = n0 + wn * 64 + (nig >> 1) * 32 + (nig & 1) * 16 + ln15;
      if (EPI == 0) {
        const int region = n0 >> 11;
        if (region == 0) {
          #pragma unroll
          for (int r = 0; r < 4; r++)
            ob0[(size_t)(mrow + r) * 2048 + ncol] = f2bf(acc[mig][nig][r]);
        } else if (region == 1) {
          #pragma unroll
          for (int r = 0; r < 4; r++)
            ob1[(size_t)(mrow + r) * 2048 + (ncol - 2048)] = f2bf(acc[mig][nig][r]);
        } else {
          const int bb = mrow >> 11, ss = mrow & 2047;
          const int ncv = ncol - 4096;
          const int hh = ncv >> 7, dd = ncv & 127;
          ushort4 v;
          v.x = f2bf(acc[mig][nig][0]); v.y = f2bf(acc[mig][nig][1]);
          v.z = f2bf(acc[mig][nig][2]); v.w = f2bf(acc[mig][nig][3]);
          *(ushort4*)(ob2 + ((size_t)((bb * 16 + hh) * 128 + dd)) * 2048 + ss) = v;
        }
      } else {
        const float bv = bias[ncol];
        #pragma unroll
        for (int r = 0; r < 4; r++) {
          float v = acc[mig][nig][r] + bv;
          v = fminf(fmaxf(v, 0.0f), 6.0f);
          ob0[(size_t)(mrow + r) * N + ncol] = f2bf(v);
        }
      }
    }
  }
}

// ====== GEMM (R8/R9 known-good): BM=256, BN=128, BK=64, 8 waves, ring-3, 1 barrier/tile ======
template <int EPI>
__global__ __launch_bounds__(512, 1)
void gemm_r3(const ushort_t* __restrict__ A, const ushort_t* __restrict__ B,
             int K, int N,
             ushort_t* ob0, ushort_t* ob1, ushort_t* ob2, float* outf,
             const float* __restrict__ res, const float* __restrict__ bias,
             int nbx) {
  constexpr int SLOT = 49152;
  __shared__ __align__(16) char smem[3 * SLOT];

  const int tid = threadIdx.x;
  const int lane = tid & 63;
  const int wid = tid >> 6;
  const int wm = wid >> 1, wn = wid & 1;
  const int ln15 = lane & 15, g = lane >> 4;

  int wg = blockIdx.x;
  const int cpx = gridDim.x >> 3;
  wg = (wg & 7) * cpx + (wg >> 3);
  const int bx = wg % nbx, by = wg / nbx;
  const int m0 = by * 256, n0 = bx * 128;

  const char* Ab = (const char*)(A + (size_t)m0 * K);
  const char* Bb = (const char*)(B + (size_t)n0 * K);
  const size_t rowb = (size_t)K * 2;
  const int NT = K >> 6;

  auto stage = [&](int t, int slot) {
    char* As = smem + slot * SLOT;
    char* Bs = As + 32768;
    const size_t kb = (size_t)t * 128;
    #pragma unroll
    for (int i = 0; i < 4; i++) {
      const int o = i * 8192 + tid * 16;
      const int row = o >> 7, col = o & 127;
      gload_lds16(Ab + (size_t)row * rowb + kb + (col ^ ((row & 7) << 4)), As + o);
    }
    #pragma unroll
    for (int i = 0; i < 2; i++) {
      const int o = i * 8192 + tid * 16;
      const int row = o >> 7, col = o & 127;
      gload_lds16(Bb + (size_t)row * rowb + kb + (col ^ ((row & 7) << 4)), Bs + o);
    }
  };

  f32x4 acc[4][4] = {};

  stage(0, 0);
  if (NT > 1) stage(1, 1);

  int slot = 0;
  for (int t = 0; t < NT; ++t) {
    if (t + 1 < NT) waitvm<6>(); else waitvm<0>();
    __builtin_amdgcn_s_barrier();

    const int slot2 = (slot + 2 >= 3) ? slot - 1 : slot + 2;
    if (t + 2 < NT) stage(t + 2, slot2);

    const char* As = smem + slot * SLOT;
    const char* Bs = As + 32768;

    bf16x8 af[4][2], bfm[4][2];
    #pragma unroll
    for (int mi = 0; mi < 4; mi++) {
      const int row = wm * 64 + mi * 16 + ln15;
      #pragma unroll
      for (int kk = 0; kk < 2; kk++)
        af[mi][kk] = *(const bf16x8*)(As + row * 128 + ((kk * 64 + g * 16) ^ ((row & 7) << 4)));
    }
    #pragma unroll
    for (int ni = 0; ni < 4; ni++) {
      const int row = wn * 64 + ni * 16 + ln15;
      #pragma unroll
      for (int kk = 0; kk < 2; kk++)
        bfm[ni][kk] = *(const bf16x8*)(Bs + row * 128 + ((kk * 64 + g * 16) ^ ((row & 7) << 4)));
    }

    __builtin_amdgcn_s_setprio(1);
    #pragma unroll
    for (int kk = 0; kk < 2; kk++)
      #pragma unroll
      for (int mi = 0; mi < 4; mi++)
        #pragma unroll
        for (int ni = 0; ni < 4; ni++)
          acc[mi][ni] = __builtin_amdgcn_mfma_f32_16x16x32_bf16(af[mi][kk], bfm[ni][kk], acc[mi][ni], 0, 0, 0);
    __builtin_amdgcn_s_setprio(0);

    slot = (slot + 1 >= 3) ? 0 : slot + 1;
  }

  #pragma unroll
  for (int mi = 0; mi < 4; mi++) {
    const int mrow = m0 + wm * 64 + mi * 16 + g * 4;
    #pragma unroll
    for (int ni = 0; ni < 4; ni++) {
      const int ncol = n0 + wn * 64 + ni * 16 + ln15;
      if (EPI == 0) {
        const int region = n0 >> 11;
        if (region == 0) {
          #pragma unroll
          for (int r = 0; r < 4; r++)
            ob0[(size_t)(mrow + r) * 2048 + ncol] = f2bf(acc[mi][ni][r]);
        } else if (region == 1) {
          #pragma unroll
          for (int r = 0; r < 4; r++)
            ob1[(size_t)(mrow + r) * 2048 + (ncol - 2048)] = f2bf(acc[mi][ni][r]);
        } else {
          const int bb = mrow >> 11, ss = mrow & 2047;
          const int ncv = ncol - 4096;
          const int hh = ncv >> 7, dd = ncv & 127;
          ushort4 v;
          v.x = f2bf(acc[mi][ni][0]); v.y = f2bf(acc[mi][ni][1]);
          v.z = f2bf(acc[mi][ni][2]); v.w = f2bf(acc[mi][ni][3]);
          *(ushort4*)(ob2 + ((size_t)((bb * 16 + hh) * 128 + dd)) * 2048 + ss) = v;
        }
      } else if (EPI == 2) {
        const float bv = bias[ncol];
        #pragma unroll
        for (int r = 0; r < 4; r++) {
          float v = acc[mi][ni][r] + bv;
          v = fminf(fmaxf(v, 0.0f), 6.0f);
          ob0[(size_t)(mrow + r) * N + ncol] = f2bf(v);
        }
      } else {
        const float bv = bias ? bias[ncol] : 0.0f;
        #pragma unroll
        for (int r = 0; r < 4; r++) {
          const size_t idx = (size_t)(mrow + r) * N + ncol;
          outf[idx] = res[idx] + acc[mi][ni][r] + bv;
        }
      }
    }
  }
}

// ------- Flash attention (causal), QBLK=128, KVBLK=64, 8 waves, 2 blocks/CU -------
__global__ __launch_bounds__(512, 2)
void attn_kernel(const unsigned short* __restrict__ Qg,
                 const unsigned short* __restrict__ Kg,
                 const unsigned short* __restrict__ Vg,
                 unsigned short* __restrict__ Og) {
  __shared__ __align__(16) char smem[65536];
  const int tid = threadIdx.x, lane = tid & 63, wid = tid >> 6;
  const int g = lane >> 4, qq = lane & 15;
  const int pairx = blockIdx.x, h = blockIdx.y, b = blockIdx.z;

  auto stage = [&](int kv0, char* kdst, char* vdst) {
    #pragma unroll
    for (int i = 0; i < 2; i++) {
      const int oo = i * 8192 + tid * 16;
      const int rK = oo >> 8;
      const int sK = (oo & 255) ^ ((rK & 7) << 4);
      gload_lds16((const char*)Kg + ((size_t)(b * 2048 + kv0 + rK) * 2048 + h * 128) * 2 + sK,
                  kdst + oo);
      const int rV = oo >> 7;
      const int sV = (oo & 127) ^ ((rV & 7) << 4);
      gload_lds16((const char*)Vg + ((size_t)((b * 16 + h) * 128 + rV) * 2048 + kv0) * 2 + sV,
                  vdst + oo);
    }
  };

  for (int half = 0; half < 2; ++half) {
    const int qb8 = half ? (15 - pairx) : pairx;
    const int q0 = qb8 * 128;
    const int myq = q0 + wid * 16 + qq;
    const int nt = 2 * qb8 + 2;

    bf16x8 qf[4];
    const unsigned short* qp = Qg + ((size_t)(b * 2048 + myq)) * 2048 + h * 128 + g * 8;
    #pragma unroll
    for (int ks = 0; ks < 4; ks++) qf[ks] = *(const bf16x8*)(qp + ks * 32);

    stage(0, smem, smem + 16384);

    float m_run = -1e30f, l_run = 0.0f;
    f32x4 oacc[8] = {};

    for (int t = 0; t < nt; ++t) {
      const int cur = t & 1;
      char* kbc = cur ? smem + 32768 : smem;
      char* vbc = cur ? smem + 49152 : smem + 16384;
      char* kbn = cur ? smem : smem + 32768;
      char* vbn = cur ? smem + 16384 : smem + 49152;

      if (t + 1 < nt) {
        stage((t + 1) * 64, kbn, vbn);
        asm volatile("s_waitcnt vmcnt(4)" ::: "memory");
      } else {
        asm volatile("s_waitcnt vmcnt(0)" ::: "memory");
      }
      __builtin_amdgcn_s_barrier();
      asm volatile("" ::: "memory");

      const int kv0 = t * 64;

      f32x4 st[4] = {};
      __builtin_amdgcn_s_setprio(1);
      #pragma unroll
      for (int ks = 0; ks < 4; ks++) {
        #pragma unroll
        for (int f = 0; f < 4; f++) {
          const int row = f * 16 + qq;
          const int cb = ks * 64 + g * 16;
          bf16x8 kf = *(const bf16x8*)(kbc + row * 256 + (cb ^ ((row & 7) << 4)));
          st[f] = __builtin_amdgcn_mfma_f32_16x16x32_bf16(kf, qf[ks], st[f], 0, 0, 0);
        }
      }
      __builtin_amdgcn_s_setprio(0);

      float p[4][4];
      float tmax = -3.0e38f;
      const bool diag = (kv0 + 63 > q0 + wid * 16);
      #pragma unroll
      for (int f = 0; f < 4; f++) {
        #pragma unroll
        for (int r = 0; r < 4; r++) {
          float v = st[f][r] * 0.08838834764831845f;
          if (diag) {
            const int kv = kv0 + f * 16 + g * 4 + r;
            if (kv > myq) v = -3.0e38f;
          }
          p[f][r] = v;
          tmax = fmaxf(tmax, v);
        }
      }
      tmax = fmaxf(tmax, __shfl_xor(tmax, 16));
      tmax = fmaxf(tmax, __shfl_xor(tmax, 32));
      const float m_new = fmaxf(m_run, tmax);
      const float sf = __expf(m_run - m_new);
      m_run = m_new;
      float tsum = 0.0f;
      #pragma unroll
      for (int f = 0; f < 4; f++) {
        #pragma unroll
        for (int r = 0; r < 4; r++) {
          p[f][r] = __expf(p[f][r] - m_new);
          tsum += p[f][r];
        }
      }
      tsum += __shfl_xor(tsum, 16);
      tsum += __shfl_xor(tsum, 32);
      l_run = l_run * sf + tsum;

      unsigned pk[4][2];
      #pragma unroll
      for (int f = 0; f < 4; f++) {
        pk[f][0] = (unsigned)f2bf(p[f][0]) | ((unsigned)f2bf(p[f][1]) << 16);
        pk[f][1] = (unsigned)f2bf(p[f][2]) | ((unsigned)f2bf(p[f][3]) << 16);
      }
      bf16x8 pa[2];
      const int sel = g >> 1;
      #pragma unroll
      for (int ks2 = 0; ks2 < 2; ks2++) {
        unsigned d[4];
        #pragma unroll
        for (int u = 0; u < 2; u++) {
          const int sl = qq + (((2 * g + u) & 3) << 4);
          const unsigned lo0 = (unsigned)__shfl((int)pk[2 * ks2][0], sl);
          const unsigned hi0 = (unsigned)__shfl((int)pk[2 * ks2 + 1][0], sl);
          const unsigned lo1 = (unsigned)__shfl((int)pk[2 * ks2][1], sl);
          const unsigned hi1 = (unsigned)__shfl((int)pk[2 * ks2 + 1][1], sl);
          d[2 * u]     = sel ? hi0 : lo0;
          d[2 * u + 1] = sel ? hi1 : lo1;
        }
        union { unsigned u[4]; bf16x8 v; } cv;
        cv.u[0] = d[0]; cv.u[1] = d[1]; cv.u[2] = d[2]; cv.u[3] = d[3];
        pa[ks2] = cv.v;
      }

      float sfr[4];
      #pragma unroll
      for (int r = 0; r < 4; r++) sfr[r] = __shfl(sf, g * 4 + r);
      #pragma unroll
      for (int nf = 0; nf < 8; nf++) {
        oacc[nf][0] *= sfr[0]; oacc[nf][1] *= sfr[1];
        oacc[nf][2] *= sfr[2]; oacc[nf][3] *= sfr[3];
      }
      __builtin_amdgcn_s_setprio(1);
      #pragma unroll
      for (int ks2 = 0; ks2 < 2; ks2++) {
        #pragma unroll
        for (int nf = 0; nf < 8; nf++) {
          const int row = nf * 16 + qq;
          const int cb = ks2 * 64 + g * 16;
          bf16x8 vf = *(const bf16x8*)(vbc + row * 128 + (cb ^ ((row & 7) << 4)));
          oacc[nf] = __builtin_amdgcn_mfma_f32_16x16x32_bf16(pa[ks2], vf, oacc[nf], 0, 0, 0);
        }
      }
      __builtin_amdgcn_s_setprio(0);

      asm volatile("" ::: "memory");
      __builtin_amdgcn_s_barrier();
    }

    asm volatile("" ::: "memory");
    const float inv = 1.0f / l_run;
    float invr[4];
    #pragma unroll
    for (int r = 0; r < 4; r++) invr[r] = __shfl(inv, g * 4 + r);

    float* Osm = (float*)smem;
    #pragma unroll
    for (int pass = 0; pass < 2; ++pass) {
      if ((wid >> 2) == pass) {
        const int w4 = wid & 3;
        #pragma unroll
        for (int nf = 0; nf < 8; nf++) {
          #pragma unroll
          for (int r = 0; r < 4; r++)
            Osm[(w4 * 16 + g * 4 + r) * 132 + nf * 16 + qq] = oacc[nf][r] * invr[r];
        }
      }
      __syncthreads();
      #pragma unroll
      for (int it = 0; it < 2; it++) {
        const int row = it * 32 + (tid >> 4);
        const int c0 = (tid & 15) * 8;
        const float* src = &Osm[row * 132 + c0];
        uint4 w;
        w.x = (unsigned)f2bf(src[0]) | ((unsigned)f2bf(src[1]) << 16);
        w.y = (unsigned)f2bf(src[2]) | ((unsigned)f2bf(src[3]) << 16);
        w.z = (unsigned)f2bf(src[4]) | ((unsigned)f2bf(src[5]) << 16);
        w.w = (unsigned)f2bf(src[6]) | ((unsigned)f2bf(src[7]) << 16);
        *(uint4*)(Og + (size_t)(b * 2048 + q0 + pass * 64 + row) * 2048 + h * 128 + c0) = w;
      }
      __syncthreads();
    }
  }
}

extern "C" void kernel_launch(void* const* d_in, const int* in_sizes, int n_in,
                              void* d_out, int out_size, void* d_ws, size_t ws_size,
                              hipStream_t stream) {
  (void)in_sizes; (void)n_in; (void)out_size; (void)ws_size;
  const float* x  = (const float*)d_in[0];
  const float* wq = (const float*)d_in[1];
  const float* wk = (const float*)d_in[2];
  const float* wv = (const float*)d_in[3];
  const float* wo = (const float*)d_in[4];
  const float* w1 = (const float*)d_in[5];
  const float* b1 = (const float*)d_in[6];
  const float* w2 = (const float*)d_in[7];
  const float* b2 = (const float*)d_in[8];
  float* out = (float*)d_out;
  char* ws = (char*)d_ws;

  // workspace layout (bytes); total = 184,549,376
  ushort_t* wqkvT = (ushort_t*)(ws + 0);            // [6144 n][2048 k] (q|k|v)
  ushort_t* woC = (ushort_t*)(ws + 25165824);       // [2048 e][2048 hk]
  ushort_t* w1T = (ushort_t*)(ws + 33554432);       // [8192 f][2048 e]
  ushort_t* w2T = (ushort_t*)(ws + 67108864);       // [2048 e][8192 f]
  ushort_t* h1  = (ushort_t*)(ws + 100663296);      // [4096][2048]
  ushort_t* Qb  = (ushort_t*)(ws + 117440512);
  ushort_t* Kb  = (ushort_t*)(ws + 134217728);
  ushort_t* Vt  = (ushort_t*)(ws + 150994944);      // [b,h,d,s]
  ushort_t* hid = h1;                                // [4096][8192] aliases h1/Q/K/V (dead)
  ushort_t* att = (ushort_t*)(ws + 167772160);
  ushort_t* h2  = att;                               // aliases att (dead then)

  const dim3 tb(32, 8);
  // weight conversion: fused QKV transposes (one launch), wo convert, w1/w2 transposes
  transpose_cvt3<<<dim3(64, 64, 3), tb, 0, stream>>>(wq, wk, wv, wqkvT);
  cvt_bf16_kernel<<<4096, 256, 0, stream>>>(wo, woC, 1048576);
  transpose_cvt<<<dim3(256, 64), tb, 0, stream>>>(w1, w1T, 2048, 8192);
  transpose_cvt<<<dim3(64, 256), tb, 0, stream>>>(w2, w2T, 8192, 2048);

  // h1 = rmsnorm(x)
  rmsnorm_kernel<<<4096, 256, 0, stream>>>(x, h1);
  // fused QKV (ring-3, 768 blocks = 3 exact rounds): Q->Qb, K->Kb, V->Vt
  gemm_r3<0><<<48 * 16, 512, 0, stream>>>(h1, wqkvT, 2048, 6144,
                                          Qb, Kb, Vt, nullptr, nullptr, nullptr, 48);
  // attention (QBLK=128, 8 waves, 2 blocks/CU)
  attn_kernel<<<dim3(8, 16, 2), 512, 0, stream>>>(Qb, Kb, Vt, att);
  // x1 = x + attn @ w_o -> d_out (fp32)
  gemm_r3<3><<<16 * 16, 512, 0, stream>>>(att, woC, 2048, 2048,
                                          nullptr, nullptr, nullptr, out, x, nullptr, 16);
  // h2 = rmsnorm(x1)
  rmsnorm_kernel<<<4096, 256, 0, stream>>>(out, h2);
  // hidden = relu6(h2 @ w1 + b1)  (8-phase 256^2, 512 blocks = 2 exact rounds)
  gemm8p<2><<<32 * 16, 512, 0, stream>>>(h2, w1T, 2048, 8192,
                                         hid, nullptr, nullptr, b1, 32);
  // out = x1 + hidden @ w2 + b2
  gemm_r3<3><<<16 * 16, 512, 0, stream>>>(hid, w2T, 8192, 2048,
                                          nullptr, nullptr, nullptr, out, out, b2, 16);
}

// Round 14
// 584.139 us; speedup vs baseline: 2.4792x; 1.0011x over previous
//
#include <hip/hip_runtime.h>
#include <hip/hip_bf16.h>
#include <stdint.h>

typedef __attribute__((ext_vector_type(8))) short bf16x8;
typedef __attribute__((ext_vector_type(4))) float f32x4;
typedef unsigned short ushort_t;

typedef __attribute__((address_space(1))) char as1_char;
typedef __attribute__((address_space(3))) char as3_char;

__device__ __forceinline__ void gload_lds16(const void* g, void* l) {
  __builtin_amdgcn_global_load_lds((as1_char*)g, (as3_char*)l, 16, 0, 0);
}

template <int N> __device__ __forceinline__ void waitvm() {
  asm volatile("s_waitcnt vmcnt(%0)" :: "n"(N) : "memory");
}

__device__ __forceinline__ unsigned short f2bf(float f) {
  union { float f; unsigned u; } c; c.f = f;
  unsigned u = c.u;
  return (unsigned short)((u + 0x7fffu + ((u >> 16) & 1u)) >> 16);
}

// ---------------- RMSNorm: fp32 [tok][2048] -> bf16 ----------------
__global__ __launch_bounds__(256)
void rmsnorm_kernel(const float* __restrict__ x, unsigned short* __restrict__ out) {
  const int tok = blockIdx.x;
  const int tid = threadIdx.x;
  const float4* xr = (const float4*)(x + (size_t)tok * 2048);
  float4 a = xr[tid];
  float4 b = xr[tid + 256];
  float s = a.x*a.x + a.y*a.y + a.z*a.z + a.w*a.w
          + b.x*b.x + b.y*b.y + b.z*b.z + b.w*b.w;
  #pragma unroll
  for (int m = 1; m < 64; m <<= 1) s += __shfl_xor(s, m);
  __shared__ float ws4[4];
  if ((tid & 63) == 0) ws4[tid >> 6] = s;
  __syncthreads();
  const float tot = ws4[0] + ws4[1] + ws4[2] + ws4[3];
  const float r = rsqrtf(tot * (1.0f / 2048.0f));
  ushort4 o1, o2;
  o1.x = f2bf(a.x * r); o1.y = f2bf(a.y * r); o1.z = f2bf(a.z * r); o1.w = f2bf(a.w * r);
  o2.x = f2bf(b.x * r); o2.y = f2bf(b.y * r); o2.z = f2bf(b.z * r); o2.w = f2bf(b.w * r);
  ushort4* orow = (ushort4*)(out + (size_t)tok * 2048);
  orow[tid] = o1;
  orow[tid + 256] = o2;
}

// ---- WIDE transpose + convert: fp32 in[R][C] -> bf16 out[C][R]; 64r x 32c tile ----
// Loads: 128B/wave-row contiguous fp32. Stores: ushort4 (8B/lane) — each 16-lane
// group writes one full 128B output segment. LDS [c][r] pad-65 (2-way alias = free).
__global__ __launch_bounds__(256)
void transpose_cvt_w(const float* __restrict__ in, unsigned short* __restrict__ out,
                     int R, int C) {
  __shared__ float t[32][65];
  const int c0 = blockIdx.x * 32, r0 = blockIdx.y * 64;
  const int tx = threadIdx.x & 31;      // c within tile
  const int ty = threadIdx.x >> 5;      // 0..7
  #pragma unroll
  for (int i = 0; i < 8; i++) {
    const int r = ty + 8 * i;
    t[tx][r] = in[(size_t)(r0 + r) * C + (c0 + tx)];
  }
  __syncthreads();
  #pragma unroll
  for (int it = 0; it < 2; it++) {
    const int slot = threadIdx.x + it * 256;   // 0..511
    const int c = slot >> 4;                   // 0..31
    const int r4 = (slot & 15) * 4;            // 0..60
    ushort4 v;
    v.x = f2bf(t[c][r4]);     v.y = f2bf(t[c][r4 + 1]);
    v.z = f2bf(t[c][r4 + 2]); v.w = f2bf(t[c][r4 + 3]);
    *(ushort4*)(out + (size_t)(c0 + c) * R + (r0 + r4)) = v;
  }
}

// ---- fused QKV wide transpose: z selects wq/wk/wv; out slices of [6144][2048] ----
__global__ __launch_bounds__(256)
void transpose_cvt3_w(const float* __restrict__ w0, const float* __restrict__ w1,
                      const float* __restrict__ w2, unsigned short* __restrict__ out) {
  __shared__ float t[32][65];
  const float* in = (blockIdx.z == 0) ? w0 : (blockIdx.z == 1) ? w1 : w2;
  unsigned short* o = out + (size_t)blockIdx.z * 2048 * 2048;
  const int c0 = blockIdx.x * 32, r0 = blockIdx.y * 64;
  const int tx = threadIdx.x & 31;
  const int ty = threadIdx.x >> 5;
  #pragma unroll
  for (int i = 0; i < 8; i++) {
    const int r = ty + 8 * i;
    t[tx][r] = in[(size_t)(r0 + r) * 2048 + (c0 + tx)];
  }
  __syncthreads();
  #pragma unroll
  for (int it = 0; it < 2; it++) {
    const int slot = threadIdx.x + it * 256;
    const int c = slot >> 4;
    const int r4 = (slot & 15) * 4;
    ushort4 v;
    v.x = f2bf(t[c][r4]);     v.y = f2bf(t[c][r4 + 1]);
    v.z = f2bf(t[c][r4 + 2]); v.w = f2bf(t[c][r4 + 3]);
    *(ushort4*)(o + (size_t)(c0 + c) * 2048 + (r0 + r4)) = v;
  }
}

// ------------- convert only: fp32 -> bf16 (layout preserved) -------------
__global__ __launch_bounds__(256)
void cvt_bf16_kernel(const float* __restrict__ in, unsigned short* __restrict__ out, int n4) {
  const int i = blockIdx.x * 256 + threadIdx.x;
  if (i < n4) {
    float4 v = ((const float4*)in)[i];
    ushort4 o; o.x = f2bf(v.x); o.y = f2bf(v.y); o.z = f2bf(v.z); o.w = f2bf(v.w);
    ((ushort4*)out)[i] = o;
  }
}

// ============== 256x256 8-phase GEMM, 8 waves (2Mx4N) — known-good ==============
template <int EPI>
__global__ __launch_bounds__(512, 1)
void gemm8p(const ushort_t* __restrict__ A, const ushort_t* __restrict__ B,
            int K, int N,
            ushort_t* ob0, ushort_t* ob1, ushort_t* ob2,
            const float* __restrict__ bias, int nbx) {
  __shared__ __align__(16) char smem[131072];
  const int tid = threadIdx.x;
  const int lane = tid & 63;
  const int wid = tid >> 6;
  const int wm = wid >> 2, wn = wid & 3;
  const int ln15 = lane & 15, g = lane >> 4;

  int wg = blockIdx.x;
  const int cpx = gridDim.x >> 3;
  wg = (wg & 7) * cpx + (wg >> 3);
  const int bx = wg % nbx, by = wg / nbx;
  const int m0 = by * 256, n0 = bx * 256;

  const char* Ab = (const char*)(A + (size_t)m0 * K);
  const char* Bb = (const char*)(B + (size_t)n0 * K);
  const size_t rowb = (size_t)K * 2;
  const int ITERS = K >> 7;

  auto stA = [&](int t, int h) {
    char* dst = smem + ((t & 1) << 16) + (h << 14);
    const size_t kb = (size_t)t << 7;
    #pragma unroll
    for (int j = 0; j < 2; j++) {
      const int o = j * 8192 + tid * 16;
      const int lr = o >> 7, col = o & 127;
      const int grow = (lr & 63) + (h << 6) + ((lr >> 6) << 7);
      gload_lds16(Ab + (size_t)grow * rowb + kb + (col ^ ((lr & 7) << 4)), dst + o);
    }
  };
  auto stB = [&](int t, int h) {
    char* dst = smem + ((t & 1) << 16) + 32768 + (h << 14);
    const size_t kb = (size_t)t << 7;
    #pragma unroll
    for (int j = 0; j < 2; j++) {
      const int o = j * 8192 + tid * 16;
      const int lr = o >> 7, col = o & 127;
      const int grow = (lr & 31) + (h << 5) + ((lr >> 5) << 6);
      gload_lds16(Bb + (size_t)grow * rowb + kb + (col ^ ((lr & 7) << 4)), dst + o);
    }
  };

  f32x4 acc[8][4] = {};
  bf16x8 af[8], bfr[4];
  const int lra = wm * 64 + ln15;
  const int lrb = wn * 32 + ln15;

  auto ldA = [&](int c, int mh) {
    const char* base = smem + (c << 16) + (mh << 14);
    #pragma unroll
    for (int mi = 0; mi < 4; mi++) {
      const int lr = lra + mi * 16;
      #pragma unroll
      for (int kk = 0; kk < 2; kk++)
        af[mi * 2 + kk] = *(const bf16x8*)(base + lr * 128 + ((kk * 64 + g * 16) ^ ((lr & 7) << 4)));
    }
  };
  auto ldB = [&](int c, int nh) {
    const char* base = smem + (c << 16) + 32768 + (nh << 14);
    #pragma unroll
    for (int ni = 0; ni < 2; ni++) {
      const int lr = lrb + ni * 16;
      #pragma unroll
      for (int kk = 0; kk < 2; kk++)
        bfr[ni * 2 + kk] = *(const bf16x8*)(base + lr * 128 + ((kk * 64 + g * 16) ^ ((lr & 7) << 4)));
    }
  };

#define MFQ(MH, NH)                                                              \
  __builtin_amdgcn_s_barrier();                                                  \
  __builtin_amdgcn_s_setprio(1);                                                 \
  _Pragma("unroll")                                                              \
  for (int kk = 0; kk < 2; kk++)                                                 \
    _Pragma("unroll")                                                            \
    for (int mi = 0; mi < 4; mi++)                                               \
      _Pragma("unroll")                                                          \
      for (int ni = 0; ni < 2; ni++)                                             \
        acc[(MH) * 4 + mi][(NH) * 2 + ni] = __builtin_amdgcn_mfma_f32_16x16x32_bf16( \
            af[mi * 2 + kk], bfr[ni * 2 + kk], acc[(MH) * 4 + mi][(NH) * 2 + ni], 0, 0, 0); \
  __builtin_amdgcn_s_setprio(0);                                                 \
  __builtin_amdgcn_s_barrier();

  stA(0, 0); stB(0, 0); stB(0, 1); stA(0, 1);
  stA(1, 0); stB(1, 1); stA(1, 1);
  waitvm<6>();
  __builtin_amdgcn_s_barrier();

  for (int i = 0; i < ITERS; ++i) {
    const int a = 2 * i, b = a + 1;
    const bool pf = (i + 1 < ITERS);
    ldA(0, 0); ldB(0, 0); stB(b, 0);
    MFQ(0, 0)
    ldB(0, 1); if (pf) stA(a + 2, 0);
    MFQ(0, 1)
    ldA(0, 1); if (pf) stB(a + 2, 1);
    MFQ(1, 1)
    ldB(0, 0); if (pf) stA(a + 2, 1);
    if (pf) waitvm<6>(); else waitvm<0>();
    MFQ(1, 0)
    ldA(1, 0); ldB(1, 0); if (pf) stB(a + 2, 0);
    MFQ(0, 0)
    ldB(1, 1); if (pf) stA(b + 2, 0);
    MFQ(0, 1)
    ldA(1, 1); if (pf) stB(b + 2, 1);
    MFQ(1, 1)
    ldB(1, 0); if (pf) stA(b + 2, 1);
    if (pf) waitvm<6>();
    MFQ(1, 0)
  }
#undef MFQ

  #pragma unroll
  for (int mig = 0; mig < 8; mig++) {
    const int mrow = m0 + wm * 128 + (mig >> 2) * 64 + (mig & 3) * 16 + g * 4;
    #pragma unroll
    for (int nig = 0; nig < 4; nig++) {
      const int ncol = n0 + wn * 64 + (nig >> 1) * 32 + (nig & 1) * 16 + ln15;
      if (EPI == 0) {
        const int region = n0 >> 11;
        if (region == 0) {
          #pragma unroll
          for (int r = 0; r < 4; r++)
            ob0[(size_t)(mrow + r) * 2048 + ncol] = f2bf(acc[mig][nig][r]);
        } else if (region == 1) {
          #pragma unroll
          for (int r = 0; r < 4; r++)
            ob1[(size_t)(mrow + r) * 2048 + (ncol - 2048)] = f2bf(acc[mig][nig][r]);
        } else {
          const int bb = mrow >> 11, ss = mrow & 2047;
          const int ncv = ncol - 4096;
          const int hh = ncv >> 7, dd = ncv & 127;
          ushort4 v;
          v.x = f2bf(acc[mig][nig][0]); v.y = f2bf(acc[mig][nig][1]);
          v.z = f2bf(acc[mig][nig][2]); v.w = f2bf(acc[mig][nig][3]);
          *(ushort4*)(ob2 + ((size_t)((bb * 16 + hh) * 128 + dd)) * 2048 + ss) = v;
        }
      } else {
        const float bv = bias[ncol];
        #pragma unroll
        for (int r = 0; r < 4; r++) {
          float v = acc[mig][nig][r] + bv;
          v = fminf(fmaxf(v, 0.0f), 6.0f);
          ob0[(size_t)(mrow + r) * N + ncol] = f2bf(v);
        }
      }
    }
  }
}

// ====== GEMM (known-good): BM=256, BN=128, BK=64, 8 waves, ring-3, 1 barrier/tile ======
template <int EPI>
__global__ __launch_bounds__(512, 1)
void gemm_r3(const ushort_t* __restrict__ A, const ushort_t* __restrict__ B,
             int K, int N,
             ushort_t* ob0, ushort_t* ob1, ushort_t* ob2, float* outf,
             const float* __restrict__ res, const float* __restrict__ bias,
             int nbx) {
  constexpr int SLOT = 49152;
  __shared__ __align__(16) char smem[3 * SLOT];

  const int tid = threadIdx.x;
  const int lane = tid & 63;
  const int wid = tid >> 6;
  const int wm = wid >> 1, wn = wid & 1;
  const int ln15 = lane & 15, g = lane >> 4;

  int wg = blockIdx.x;
  const int cpx = gridDim.x >> 3;
  wg = (wg & 7) * cpx + (wg >> 3);
  const int bx = wg % nbx, by = wg / nbx;
  const int m0 = by * 256, n0 = bx * 128;

  const char* Ab = (const char*)(A + (size_t)m0 * K);
  const char* Bb = (const char*)(B + (size_t)n0 * K);
  const size_t rowb = (size_t)K * 2;
  const int NT = K >> 6;

  auto stage = [&](int t, int slot) {
    char* As = smem + slot * SLOT;
    char* Bs = As + 32768;
    const size_t kb = (size_t)t * 128;
    #pragma unroll
    for (int i = 0; i < 4; i++) {
      const int o = i * 8192 + tid * 16;
      const int row = o >> 7, col = o & 127;
      gload_lds16(Ab + (size_t)row * rowb + kb + (col ^ ((row & 7) << 4)), As + o);
    }
    #pragma unroll
    for (int i = 0; i < 2; i++) {
      const int o = i * 8192 + tid * 16;
      const int row = o >> 7, col = o & 127;
      gload_lds16(Bb + (size_t)row * rowb + kb + (col ^ ((row & 7) << 4)), Bs + o);
    }
  };

  f32x4 acc[4][4] = {};

  stage(0, 0);
  if (NT > 1) stage(1, 1);

  int slot = 0;
  for (int t = 0; t < NT; ++t) {
    if (t + 1 < NT) waitvm<6>(); else waitvm<0>();
    __builtin_amdgcn_s_barrier();

    const int slot2 = (slot + 2 >= 3) ? slot - 1 : slot + 2;
    if (t + 2 < NT) stage(t + 2, slot2);

    const char* As = smem + slot * SLOT;
    const char* Bs = As + 32768;

    bf16x8 af[4][2], bfm[4][2];
    #pragma unroll
    for (int mi = 0; mi < 4; mi++) {
      const int row = wm * 64 + mi * 16 + ln15;
      #pragma unroll
      for (int kk = 0; kk < 2; kk++)
        af[mi][kk] = *(const bf16x8*)(As + row * 128 + ((kk * 64 + g * 16) ^ ((row & 7) << 4)));
    }
    #pragma unroll
    for (int ni = 0; ni < 4; ni++) {
      const int row = wn * 64 + ni * 16 + ln15;
      #pragma unroll
      for (int kk = 0; kk < 2; kk++)
        bfm[ni][kk] = *(const bf16x8*)(Bs + row * 128 + ((kk * 64 + g * 16) ^ ((row & 7) << 4)));
    }

    __builtin_amdgcn_s_setprio(1);
    #pragma unroll
    for (int kk = 0; kk < 2; kk++)
      #pragma unroll
      for (int mi = 0; mi < 4; mi++)
        #pragma unroll
        for (int ni = 0; ni < 4; ni++)
          acc[mi][ni] = __builtin_amdgcn_mfma_f32_16x16x32_bf16(af[mi][kk], bfm[ni][kk], acc[mi][ni], 0, 0, 0);
    __builtin_amdgcn_s_setprio(0);

    slot = (slot + 1 >= 3) ? 0 : slot + 1;
  }

  #pragma unroll
  for (int mi = 0; mi < 4; mi++) {
    const int mrow = m0 + wm * 64 + mi * 16 + g * 4;
    #pragma unroll
    for (int ni = 0; ni < 4; ni++) {
      const int ncol = n0 + wn * 64 + ni * 16 + ln15;
      if (EPI == 0) {
        const int region = n0 >> 11;
        if (region == 0) {
          #pragma unroll
          for (int r = 0; r < 4; r++)
            ob0[(size_t)(mrow + r) * 2048 + ncol] = f2bf(acc[mi][ni][r]);
        } else if (region == 1) {
          #pragma unroll
          for (int r = 0; r < 4; r++)
            ob1[(size_t)(mrow + r) * 2048 + (ncol - 2048)] = f2bf(acc[mi][ni][r]);
        } else {
          const int bb = mrow >> 11, ss = mrow & 2047;
          const int ncv = ncol - 4096;
          const int hh = ncv >> 7, dd = ncv & 127;
          ushort4 v;
          v.x = f2bf(acc[mi][ni][0]); v.y = f2bf(acc[mi][ni][1]);
          v.z = f2bf(acc[mi][ni][2]); v.w = f2bf(acc[mi][ni][3]);
          *(ushort4*)(ob2 + ((size_t)((bb * 16 + hh) * 128 + dd)) * 2048 + ss) = v;
        }
      } else if (EPI == 2) {
        const float bv = bias[ncol];
        #pragma unroll
        for (int r = 0; r < 4; r++) {
          float v = acc[mi][ni][r] + bv;
          v = fminf(fmaxf(v, 0.0f), 6.0f);
          ob0[(size_t)(mrow + r) * N + ncol] = f2bf(v);
        }
      } else {
        const float bv = bias ? bias[ncol] : 0.0f;
        #pragma unroll
        for (int r = 0; r < 4; r++) {
          const size_t idx = (size_t)(mrow + r) * N + ncol;
          outf[idx] = res[idx] + acc[mi][ni][r] + bv;
        }
      }
    }
  }
}

// ------- Flash attention (causal), QBLK=128, KVBLK=64, 8 waves, 2 blocks/CU -------
__global__ __launch_bounds__(512, 2)
void attn_kernel(const unsigned short* __restrict__ Qg,
                 const unsigned short* __restrict__ Kg,
                 const unsigned short* __restrict__ Vg,
                 unsigned short* __restrict__ Og) {
  __shared__ __align__(16) char smem[65536];
  const int tid = threadIdx.x, lane = tid & 63, wid = tid >> 6;
  const int g = lane >> 4, qq = lane & 15;
  const int pairx = blockIdx.x, h = blockIdx.y, b = blockIdx.z;

  auto stage = [&](int kv0, char* kdst, char* vdst) {
    #pragma unroll
    for (int i = 0; i < 2; i++) {
      const int oo = i * 8192 + tid * 16;
      const int rK = oo >> 8;
      const int sK = (oo & 255) ^ ((rK & 7) << 4);
      gload_lds16((const char*)Kg + ((size_t)(b * 2048 + kv0 + rK) * 2048 + h * 128) * 2 + sK,
                  kdst + oo);
      const int rV = oo >> 7;
      const int sV = (oo & 127) ^ ((rV & 7) << 4);
      gload_lds16((const char*)Vg + ((size_t)((b * 16 + h) * 128 + rV) * 2048 + kv0) * 2 + sV,
                  vdst + oo);
    }
  };

  for (int half = 0; half < 2; ++half) {
    const int qb8 = half ? (15 - pairx) : pairx;
    const int q0 = qb8 * 128;
    const int myq = q0 + wid * 16 + qq;
    const int nt = 2 * qb8 + 2;

    bf16x8 qf[4];
    const unsigned short* qp = Qg + ((size_t)(b * 2048 + myq)) * 2048 + h * 128 + g * 8;
    #pragma unroll
    for (int ks = 0; ks < 4; ks++) qf[ks] = *(const bf16x8*)(qp + ks * 32);

    stage(0, smem, smem + 16384);

    float m_run = -1e30f, l_run = 0.0f;
    f32x4 oacc[8] = {};

    for (int t = 0; t < nt; ++t) {
      const int cur = t & 1;
      char* kbc = cur ? smem + 32768 : smem;
      char* vbc = cur ? smem + 49152 : smem + 16384;
      char* kbn = cur ? smem : smem + 32768;
      char* vbn = cur ? smem + 16384 : smem + 49152;

      if (t + 1 < nt) {
        stage((t + 1) * 64, kbn, vbn);
        asm volatile("s_waitcnt vmcnt(4)" ::: "memory");
      } else {
        asm volatile("s_waitcnt vmcnt(0)" ::: "memory");
      }
      __builtin_amdgcn_s_barrier();
      asm volatile("" ::: "memory");

      const int kv0 = t * 64;

      f32x4 st[4] = {};
      __builtin_amdgcn_s_setprio(1);
      #pragma unroll
      for (int ks = 0; ks < 4; ks++) {
        #pragma unroll
        for (int f = 0; f < 4; f++) {
          const int row = f * 16 + qq;
          const int cb = ks * 64 + g * 16;
          bf16x8 kf = *(const bf16x8*)(kbc + row * 256 + (cb ^ ((row & 7) << 4)));
          st[f] = __builtin_amdgcn_mfma_f32_16x16x32_bf16(kf, qf[ks], st[f], 0, 0, 0);
        }
      }
      __builtin_amdgcn_s_setprio(0);

      float p[4][4];
      float tmax = -3.0e38f;
      const bool diag = (kv0 + 63 > q0 + wid * 16);
      #pragma unroll
      for (int f = 0; f < 4; f++) {
        #pragma unroll
        for (int r = 0; r < 4; r++) {
          float v = st[f][r] * 0.08838834764831845f;
          if (diag) {
            const int kv = kv0 + f * 16 + g * 4 + r;
            if (kv > myq) v = -3.0e38f;
          }
          p[f][r] = v;
          tmax = fmaxf(tmax, v);
        }
      }
      tmax = fmaxf(tmax, __shfl_xor(tmax, 16));
      tmax = fmaxf(tmax, __shfl_xor(tmax, 32));
      const float m_new = fmaxf(m_run, tmax);
      const float sf = __expf(m_run - m_new);
      m_run = m_new;
      float tsum = 0.0f;
      #pragma unroll
      for (int f = 0; f < 4; f++) {
        #pragma unroll
        for (int r = 0; r < 4; r++) {
          p[f][r] = __expf(p[f][r] - m_new);
          tsum += p[f][r];
        }
      }
      tsum += __shfl_xor(tsum, 16);
      tsum += __shfl_xor(tsum, 32);
      l_run = l_run * sf + tsum;

      unsigned pk[4][2];
      #pragma unroll
      for (int f = 0; f < 4; f++) {
        pk[f][0] = (unsigned)f2bf(p[f][0]) | ((unsigned)f2bf(p[f][1]) << 16);
        pk[f][1] = (unsigned)f2bf(p[f][2]) | ((unsigned)f2bf(p[f][3]) << 16);
      }
      bf16x8 pa[2];
      const int sel = g >> 1;
      #pragma unroll
      for (int ks2 = 0; ks2 < 2; ks2++) {
        unsigned d[4];
        #pragma unroll
        for (int u = 0; u < 2; u++) {
          const int sl = qq + (((2 * g + u) & 3) << 4);
          const unsigned lo0 = (unsigned)__shfl((int)pk[2 * ks2][0], sl);
          const unsigned hi0 = (unsigned)__shfl((int)pk[2 * ks2 + 1][0], sl);
          const unsigned lo1 = (unsigned)__shfl((int)pk[2 * ks2][1], sl);
          const unsigned hi1 = (unsigned)__shfl((int)pk[2 * ks2 + 1][1], sl);
          d[2 * u]     = sel ? hi0 : lo0;
          d[2 * u + 1] = sel ? hi1 : lo1;
        }
        union { unsigned u[4]; bf16x8 v; } cv;
        cv.u[0] = d[0]; cv.u[1] = d[1]; cv.u[2] = d[2]; cv.u[3] = d[3];
        pa[ks2] = cv.v;
      }

      float sfr[4];
      #pragma unroll
      for (int r = 0; r < 4; r++) sfr[r] = __shfl(sf, g * 4 + r);
      #pragma unroll
      for (int nf = 0; nf < 8; nf++) {
        oacc[nf][0] *= sfr[0]; oacc[nf][1] *= sfr[1];
        oacc[nf][2] *= sfr[2]; oacc[nf][3] *= sfr[3];
      }
      __builtin_amdgcn_s_setprio(1);
      #pragma unroll
      for (int ks2 = 0; ks2 < 2; ks2++) {
        #pragma unroll
        for (int nf = 0; nf < 8; nf++) {
          const int row = nf * 16 + qq;
          const int cb = ks2 * 64 + g * 16;
          bf16x8 vf = *(const bf16x8*)(vbc + row * 128 + (cb ^ ((row & 7) << 4)));
          oacc[nf] = __builtin_amdgcn_mfma_f32_16x16x32_bf16(pa[ks2], vf, oacc[nf], 0, 0, 0);
        }
      }
      __builtin_amdgcn_s_setprio(0);

      asm volatile("" ::: "memory");
      __builtin_amdgcn_s_barrier();
    }

    asm volatile("" ::: "memory");
    const float inv = 1.0f / l_run;
    float invr[4];
    #pragma unroll
    for (int r = 0; r < 4; r++) invr[r] = __shfl(inv, g * 4 + r);

    float* Osm = (float*)smem;
    #pragma unroll
    for (int pass = 0; pass < 2; ++pass) {
      if ((wid >> 2) == pass) {
        const int w4 = wid & 3;
        #pragma unroll
        for (int nf = 0; nf < 8; nf++) {
          #pragma unroll
          for (int r = 0; r < 4; r++)
            Osm[(w4 * 16 + g * 4 + r) * 132 + nf * 16 + qq] = oacc[nf][r] * invr[r];
        }
      }
      __syncthreads();
      #pragma unroll
      for (int it = 0; it < 2; it++) {
        const int row = it * 32 + (tid >> 4);
        const int c0 = (tid & 15) * 8;
        const float* src = &Osm[row * 132 + c0];
        uint4 w;
        w.x = (unsigned)f2bf(src[0]) | ((unsigned)f2bf(src[1]) << 16);
        w.y = (unsigned)f2bf(src[2]) | ((unsigned)f2bf(src[3]) << 16);
        w.z = (unsigned)f2bf(src[4]) | ((unsigned)f2bf(src[5]) << 16);
        w.w = (unsigned)f2bf(src[6]) | ((unsigned)f2bf(src[7]) << 16);
        *(uint4*)(Og + (size_t)(b * 2048 + q0 + pass * 64 + row) * 2048 + h * 128 + c0) = w;
      }
      __syncthreads();
    }
  }
}

extern "C" void kernel_launch(void* const* d_in, const int* in_sizes, int n_in,
                              void* d_out, int out_size, void* d_ws, size_t ws_size,
                              hipStream_t stream) {
  (void)in_sizes; (void)n_in; (void)out_size; (void)ws_size;
  const float* x  = (const float*)d_in[0];
  const float* wq = (const float*)d_in[1];
  const float* wk = (const float*)d_in[2];
  const float* wv = (const float*)d_in[3];
  const float* wo = (const float*)d_in[4];
  const float* w1 = (const float*)d_in[5];
  const float* b1 = (const float*)d_in[6];
  const float* w2 = (const float*)d_in[7];
  const float* b2 = (const float*)d_in[8];
  float* out = (float*)d_out;
  char* ws = (char*)d_ws;

  // workspace layout (bytes); total = 184,549,376
  ushort_t* wqkvT = (ushort_t*)(ws + 0);            // [6144 n][2048 k] (q|k|v)
  ushort_t* woC = (ushort_t*)(ws + 25165824);       // [2048 e][2048 hk]
  ushort_t* w1T = (ushort_t*)(ws + 33554432);       // [8192 f][2048 e]
  ushort_t* w2T = (ushort_t*)(ws + 67108864);       // [2048 e][8192 f]
  ushort_t* h1  = (ushort_t*)(ws + 100663296);      // [4096][2048]
  ushort_t* Qb  = (ushort_t*)(ws + 117440512);
  ushort_t* Kb  = (ushort_t*)(ws + 134217728);
  ushort_t* Vt  = (ushort_t*)(ws + 150994944);      // [b,h,d,s]
  ushort_t* hid = h1;                                // [4096][8192] aliases h1/Q/K/V (dead)
  ushort_t* att = (ushort_t*)(ws + 167772160);
  ushort_t* h2  = att;                               // aliases att (dead then)

  // weight conversion — wide transposes (ushort4 stores)
  transpose_cvt3_w<<<dim3(64, 32, 3), 256, 0, stream>>>(wq, wk, wv, wqkvT);
  cvt_bf16_kernel<<<4096, 256, 0, stream>>>(wo, woC, 1048576);
  transpose_cvt_w<<<dim3(256, 32), 256, 0, stream>>>(w1, w1T, 2048, 8192);
  transpose_cvt_w<<<dim3(64, 128), 256, 0, stream>>>(w2, w2T, 8192, 2048);

  // h1 = rmsnorm(x)
  rmsnorm_kernel<<<4096, 256, 0, stream>>>(x, h1);
  // fused QKV (ring-3, 768 blocks = 3 exact rounds): Q->Qb, K->Kb, V->Vt
  gemm_r3<0><<<48 * 16, 512, 0, stream>>>(h1, wqkvT, 2048, 6144,
                                          Qb, Kb, Vt, nullptr, nullptr, nullptr, 48);
  // attention (QBLK=128, 8 waves, 2 blocks/CU)
  attn_kernel<<<dim3(8, 16, 2), 512, 0, stream>>>(Qb, Kb, Vt, att);
  // x1 = x + attn @ w_o -> d_out (fp32)
  gemm_r3<3><<<16 * 16, 512, 0, stream>>>(att, woC, 2048, 2048,
                                          nullptr, nullptr, nullptr, out, x, nullptr, 16);
  // h2 = rmsnorm(x1)
  rmsnorm_kernel<<<4096, 256, 0, stream>>>(out, h2);
  // hidden = relu6(h2 @ w1 + b1)  (8-phase 256^2, 512 blocks = 2 exact rounds)
  gemm8p<2><<<32 * 16, 512, 0, stream>>>(h2, w1T, 2048, 8192,
                                         hid, nullptr, nullptr, b1, 32);
  // out = x1 + hidden @ w2 + b2
  gemm_r3<3><<<16 * 16, 512, 0, stream>>>(hid, w2T, 8192, 2048,
                                          nullptr, nullptr, nullptr, out, out, b2, 16);
}